// Round 3
// baseline (3131.704 us; speedup 1.0000x reference)
//
#include <hip/hip_runtime.h>
#include <math.h>

#define N_ENTS 50000
#define N_RELS 500
#define N_ALL  50500
#define EMB    256
#define NEDGE  400000
#define BATCH  512
#define BN_EPS 1e-5f

// LDS row stride (floats) for 128-wide tiles: multiple of 4 (16B alignment for
// ds_read_b128) and ≡4 mod 8 so the transposed A-store is only a 2-way
// (free) bank conflict.
#define LDSS 132

// ---------------------------------------------------------------------------
// Build hamilton matrix H (4P x 256) from W (P x 256), quaternion structure.
// ---------------------------------------------------------------------------
__global__ __launch_bounds__(256) void build_hamilton_kernel(
    const float* __restrict__ W, float* __restrict__ H, int P) {
    int idx = blockIdx.x * 256 + threadIdx.x;
    int total = 4 * P * 256;
    if (idx >= total) return;
    int row = idx >> 8;
    int cc  = idx & 255;
    int a = row / P, p = row % P;
    int c = cc >> 6, s = cc & 63;
    const int  comp[4][4] = {{0,1,2,3},{1,0,3,2},{2,3,0,1},{3,2,1,0}};
    const float sgn[4][4] = {{1.f,1.f,1.f,1.f},
                             {-1.f,1.f,1.f,-1.f},
                             {-1.f,-1.f,1.f,1.f},
                             {-1.f,1.f,-1.f,1.f}};
    H[idx] = sgn[a][c] * W[p * 256 + comp[a][c] * 64 + s];
}

// ---------------------------------------------------------------------------
// 128x128-tile f32 GEMM inner step (8x8 acc per thread, BK=16).
// Thread (tx,ty). Row m = ty*4 + (i&3) + (i>>2)*64, col n = tx*4 + (j&3) +
// (j>>2)*64.
// ---------------------------------------------------------------------------
__device__ __forceinline__ void mm_inner(const float* As, const float* Bs,
                                         int tx, int ty, float acc[8][8]) {
#pragma unroll
    for (int k = 0; k < 16; k++) {
        const float4 a0 = *(const float4*)&As[k * LDSS + ty * 4];
        const float4 a1 = *(const float4*)&As[k * LDSS + ty * 4 + 64];
        const float4 b0 = *(const float4*)&Bs[k * LDSS + tx * 4];
        const float4 b1 = *(const float4*)&Bs[k * LDSS + tx * 4 + 64];
        float a[8] = {a0.x, a0.y, a0.z, a0.w, a1.x, a1.y, a1.z, a1.w};
        float b[8] = {b0.x, b0.y, b0.z, b0.w, b1.x, b1.y, b1.z, b1.w};
#pragma unroll
        for (int i = 0; i < 8; i++)
#pragma unroll
            for (int j = 0; j < 8; j++)
                acc[i][j] = fmaf(a[i], b[j], acc[i][j]);
    }
}

// Transposed A-tile store helper: scalar writes, 2-way (free) conflicts.
__device__ __forceinline__ void store_a_frag(float* As, int m, int kq,
                                             const float4& v) {
    As[(kq * 4 + 0) * LDSS + m] = v.x;
    As[(kq * 4 + 1) * LDSS + m] = v.y;
    As[(kq * 4 + 2) * LDSS + m] = v.z;
    As[(kq * 4 + 3) * LDSS + m] = v.w;
}

// ---------------------------------------------------------------------------
// Generic f32 NN GEMM: C[M,N] = A[M,K] @ B[K,N]. N multiple of 128,
// K multiple of 16 (>=32), M arbitrary. Register-staged double-buffered LDS,
// ONE barrier per K-step.
// ---------------------------------------------------------------------------
__global__ __launch_bounds__(256) void gemm_nn_kernel(
    const float* __restrict__ A, const float* __restrict__ B,
    float* __restrict__ C, int M, int K, int N) {
    __shared__ float As[2][16 * LDSS];
    __shared__ float Bs[2][16 * LDSS];
    int tid = threadIdx.x;
    int tx = tid & 15, ty = tid >> 4;
    int bm0 = blockIdx.y * 128;
    int bn0 = blockIdx.x * 128;
    float acc[8][8] = {};

    // Prologue: tile 0 straight to LDS buffer 0.
#pragma unroll
    for (int u = 0; u < 2; u++) {
        int idx = tid + u * 256;
        int m = idx >> 2, kq = idx & 3;
        int gm = bm0 + m;
        float4 v = make_float4(0.f, 0.f, 0.f, 0.f);
        if (gm < M) v = *(const float4*)&A[(long)gm * K + kq * 4];
        store_a_frag(As[0], m, kq, v);
        int kb = idx >> 5, nq = idx & 31;
        float4 w = *(const float4*)&B[(long)kb * N + bn0 + nq * 4];
        *(float4*)&Bs[0][kb * LDSS + nq * 4] = w;
    }
    __syncthreads();

    int p = 0;
    for (int k0 = 16; k0 < K; k0 += 16) {
        // Issue next-tile global loads first: latency hides under compute.
        float4 va[2], vb[2];
#pragma unroll
        for (int u = 0; u < 2; u++) {
            int idx = tid + u * 256;
            int m = idx >> 2, kq = idx & 3;
            int gm = bm0 + m;
            va[u] = make_float4(0.f, 0.f, 0.f, 0.f);
            if (gm < M) va[u] = *(const float4*)&A[(long)gm * K + k0 + kq * 4];
            int kb = idx >> 5, nq = idx & 31;
            vb[u] = *(const float4*)&B[(long)(k0 + kb) * N + bn0 + nq * 4];
        }
        // Compute on current buffer.
        mm_inner(As[p], Bs[p], tx, ty, acc);
        // Write staged regs to the alternate buffer.
#pragma unroll
        for (int u = 0; u < 2; u++) {
            int idx = tid + u * 256;
            int m = idx >> 2, kq = idx & 3;
            store_a_frag(As[p ^ 1], m, kq, va[u]);
            int kb = idx >> 5, nq = idx & 31;
            *(float4*)&Bs[p ^ 1][kb * LDSS + nq * 4] = vb[u];
        }
        __syncthreads();
        p ^= 1;
    }
    mm_inner(As[p], Bs[p], tx, ty, acc);

#pragma unroll
    for (int i = 0; i < 8; i++) {
        int gm = bm0 + ty * 4 + (i & 3) + (i >> 2) * 64;
        if (gm < M) {
#pragma unroll
            for (int jq = 0; jq < 2; jq++) {
                float4 v = make_float4(acc[i][jq * 4 + 0], acc[i][jq * 4 + 1],
                                       acc[i][jq * 4 + 2], acc[i][jq * 4 + 3]);
                *(float4*)&C[(long)gm * N + bn0 + tx * 4 + jq * 64] = v;
            }
        }
    }
}

// ---------------------------------------------------------------------------
// Lin GEMM: C[50000,256] = Xcat[50000,512] @ B[512,256]; Xcat column
// interleave folded into the A loader. Same double-buffered schedule.
// ---------------------------------------------------------------------------
__device__ __forceinline__ float4 lin_a_load(const float* __restrict__ Xef,
                                             const float* __restrict__ Xrf,
                                             int gm, int kk, int M) {
    // kk is a multiple of 4; a float4 never crosses a 64-chunk boundary.
    int chunk = kk >> 6, s = kk & 63;
    const float* src = (chunk & 1) ? Xrf : Xef;
    float4 v = make_float4(0.f, 0.f, 0.f, 0.f);
    if (gm < M) v = *(const float4*)&src[(long)gm * 256 + (chunk >> 1) * 64 + s];
    return v;
}

__global__ __launch_bounds__(256) void gemm_lin_kernel(
    const float* __restrict__ Xef, const float* __restrict__ Xrf,
    const float* __restrict__ B, float* __restrict__ C, int M) {
    const int K = 512, N = 256;
    __shared__ float As[2][16 * LDSS];
    __shared__ float Bs[2][16 * LDSS];
    int tid = threadIdx.x;
    int tx = tid & 15, ty = tid >> 4;
    int bm0 = blockIdx.y * 128;
    int bn0 = blockIdx.x * 128;
    float acc[8][8] = {};

#pragma unroll
    for (int u = 0; u < 2; u++) {
        int idx = tid + u * 256;
        int m = idx >> 2, kq = idx & 3;
        float4 v = lin_a_load(Xef, Xrf, bm0 + m, kq * 4, M);
        store_a_frag(As[0], m, kq, v);
        int kb = idx >> 5, nq = idx & 31;
        float4 w = *(const float4*)&B[(long)kb * N + bn0 + nq * 4];
        *(float4*)&Bs[0][kb * LDSS + nq * 4] = w;
    }
    __syncthreads();

    int p = 0;
    for (int k0 = 16; k0 < K; k0 += 16) {
        float4 va[2], vb[2];
#pragma unroll
        for (int u = 0; u < 2; u++) {
            int idx = tid + u * 256;
            int m = idx >> 2, kq = idx & 3;
            va[u] = lin_a_load(Xef, Xrf, bm0 + m, k0 + kq * 4, M);
            int kb = idx >> 5, nq = idx & 31;
            vb[u] = *(const float4*)&B[(long)(k0 + kb) * N + bn0 + nq * 4];
        }
        mm_inner(As[p], Bs[p], tx, ty, acc);
#pragma unroll
        for (int u = 0; u < 2; u++) {
            int idx = tid + u * 256;
            int m = idx >> 2, kq = idx & 3;
            store_a_frag(As[p ^ 1], m, kq, va[u]);
            int kb = idx >> 5, nq = idx & 31;
            *(float4*)&Bs[p ^ 1][kb * LDSS + nq * 4] = vb[u];
        }
        __syncthreads();
        p ^= 1;
    }
    mm_inner(As[p], Bs[p], tx, ty, acc);

#pragma unroll
    for (int i = 0; i < 8; i++) {
        int gm = bm0 + ty * 4 + (i & 3) + (i >> 2) * 64;
        if (gm < M) {
#pragma unroll
            for (int jq = 0; jq < 2; jq++) {
                float4 v = make_float4(acc[i][jq * 4 + 0], acc[i][jq * 4 + 1],
                                       acc[i][jq * 4 + 2], acc[i][jq * 4 + 3]);
                *(float4*)&C[(long)gm * N + bn0 + tx * 4 + jq * 64] = v;
            }
        }
    }
}

// ---------------------------------------------------------------------------
// Score GEMM (NT) + sigmoid: out[b,e] = sigmoid(dot(hrn[b,:], X[e,:]))
// A = hrn (512,256); B = X (50000,256); both k-major rows, both stored
// transposed into LDS. Same double-buffered schedule. K = 256 fixed.
// ---------------------------------------------------------------------------
__global__ __launch_bounds__(256) void gemm_nt_sig_kernel(
    const float* __restrict__ A,   // hrn (512,256)
    const float* __restrict__ Bt,  // X (50000,256)
    float* __restrict__ out) {
    __shared__ float As[2][16 * LDSS];
    __shared__ float Bs[2][16 * LDSS];
    int tid = threadIdx.x;
    int tx = tid & 15, ty = tid >> 4;
    int bm0 = blockIdx.y * 128;  // batch (exact: 512/128 = 4)
    int bn0 = blockIdx.x * 128;  // ents
    float acc[8][8] = {};

#pragma unroll
    for (int u = 0; u < 2; u++) {
        int idx = tid + u * 256;
        int m = idx >> 2, kq = idx & 3;
        float4 va = *(const float4*)&A[(long)(bm0 + m) * 256 + kq * 4];
        store_a_frag(As[0], m, kq, va);
        int gn = bn0 + m;
        float4 vb = make_float4(0.f, 0.f, 0.f, 0.f);
        if (gn < N_ENTS) vb = *(const float4*)&Bt[(long)gn * 256 + kq * 4];
        store_a_frag(Bs[0], m, kq, vb);
    }
    __syncthreads();

    int p = 0;
    for (int k0 = 16; k0 < 256; k0 += 16) {
        float4 va[2], vb[2];
#pragma unroll
        for (int u = 0; u < 2; u++) {
            int idx = tid + u * 256;
            int m = idx >> 2, kq = idx & 3;
            va[u] = *(const float4*)&A[(long)(bm0 + m) * 256 + k0 + kq * 4];
            int gn = bn0 + m;
            vb[u] = make_float4(0.f, 0.f, 0.f, 0.f);
            if (gn < N_ENTS)
                vb[u] = *(const float4*)&Bt[(long)gn * 256 + k0 + kq * 4];
        }
        mm_inner(As[p], Bs[p], tx, ty, acc);
#pragma unroll
        for (int u = 0; u < 2; u++) {
            int idx = tid + u * 256;
            int m = idx >> 2, kq = idx & 3;
            store_a_frag(As[p ^ 1], m, kq, va[u]);
            store_a_frag(Bs[p ^ 1], m, kq, vb[u]);
        }
        __syncthreads();
        p ^= 1;
    }
    mm_inner(As[p], Bs[p], tx, ty, acc);

#pragma unroll
    for (int i = 0; i < 8; i++) {
        int b = bm0 + ty * 4 + (i & 3) + (i >> 2) * 64;
#pragma unroll
        for (int jq = 0; jq < 2; jq++) {
            int e = bn0 + tx * 4 + jq * 64;
            if (e < N_ENTS) {  // N_ENTS % 4 == 0, whole float4 valid
                float4 v;
                v.x = 1.f / (1.f + __expf(-acc[i][jq * 4 + 0]));
                v.y = 1.f / (1.f + __expf(-acc[i][jq * 4 + 1]));
                v.z = 1.f / (1.f + __expf(-acc[i][jq * 4 + 2]));
                v.w = 1.f / (1.f + __expf(-acc[i][jq * 4 + 3]));
                *(float4*)&out[(long)b * N_ENTS + e] = v;
            }
        }
    }
}

// ---------------------------------------------------------------------------
// CSR build: histogram, single-block exclusive scan, ticket scatter.
// ---------------------------------------------------------------------------
__global__ __launch_bounds__(256) void hist_kernel(
    const int* __restrict__ rows, int* __restrict__ cnt, int n_edges) {
    int e = blockIdx.x * 256 + threadIdx.x;
    if (e < n_edges) atomicAdd(&cnt[rows[e]], 1);
}

// Single block of 1024 threads; n up to ~52k. off[0..n] exclusive offsets.
__global__ __launch_bounds__(1024) void exscan_kernel(
    const int* __restrict__ cnt, int n, int* __restrict__ off) {
    __shared__ int part[1024];
    int t = threadIdx.x;
    int chunk = (n + 1023) / 1024;
    int lo = t * chunk;
    int hi = lo + chunk; if (hi > n) hi = n;
    int s = 0;
    for (int i = lo; i < hi; i++) s += cnt[i];
    part[t] = s;
    __syncthreads();
    for (int d = 1; d < 1024; d <<= 1) {
        int v = (t >= d) ? part[t - d] : 0;
        __syncthreads();
        part[t] += v;
        __syncthreads();
    }
    int base = (t == 0) ? 0 : part[t - 1];
    for (int i = lo; i < hi; i++) {
        off[i] = base;
        base += cnt[i];
    }
    if (hi >= n) off[n] = base;  // all such threads hold the grand total
}

__global__ __launch_bounds__(256) void scatter_kernel(
    const int* __restrict__ rows, const int* __restrict__ cols,
    const float* __restrict__ vals, int* __restrict__ cursor,
    int* __restrict__ csr_cols, float* __restrict__ csr_vals, int n_edges) {
    int e = blockIdx.x * 256 + threadIdx.x;
    if (e >= n_edges) return;
    int r = rows[e];
    int p = atomicAdd(&cursor[r], 1);
    csr_cols[p] = cols[e];
    csr_vals[p] = vals[e];
}

// ---------------------------------------------------------------------------
// CSR aggregation: one 64-lane wave per row, lane owns 4 consecutive floats.
// agg[row,:] = sum_e vals[e] * support[cols[e],:]  (writes zeros for empty rows)
// ---------------------------------------------------------------------------
__global__ __launch_bounds__(256) void csr_agg_kernel(
    const float* __restrict__ support, const int* __restrict__ off,
    const int* __restrict__ ccols, const float* __restrict__ cvals,
    float* __restrict__ agg, int n_rows) {
    int gid = blockIdx.x * 256 + threadIdx.x;
    int row = gid >> 6;
    int lane = gid & 63;
    if (row >= n_rows) return;
    int beg = off[row], end = off[row + 1];
    float4 acc = {0.f, 0.f, 0.f, 0.f};
    for (int e = beg; e < end; e++) {
        int c = ccols[e];
        float v = cvals[e];
        const float4 s = *(const float4*)(support + (long)c * 256 + lane * 4);
        acc.x = fmaf(v, s.x, acc.x);
        acc.y = fmaf(v, s.y, acc.y);
        acc.z = fmaf(v, s.z, acc.z);
        acc.w = fmaf(v, s.w, acc.w);
    }
    *(float4*)(agg + (long)row * 256 + lane * 4) = acc;
}

// ---------------------------------------------------------------------------
// Column stats + BN apply (+ optional tanh)
// ---------------------------------------------------------------------------
__global__ __launch_bounds__(256) void bn_stats_kernel(
    const float* __restrict__ x, int n, float* __restrict__ stats) {
    int col = threadIdx.x;
    int r0 = blockIdx.x * 256;
    int r1 = r0 + 256;
    if (r1 > n) r1 = n;
    float s = 0.f, sq = 0.f;
    for (int r = r0; r < r1; r++) {
        float v = x[(long)r * 256 + col];
        s += v;
        sq += v * v;
    }
    atomicAdd(&stats[col], s);
    atomicAdd(&stats[256 + col], sq);
}

template <bool TANH>
__global__ __launch_bounds__(256) void bn_apply_kernel(
    const float* __restrict__ x, float* __restrict__ y, int n,
    const float* __restrict__ gamma, const float* __restrict__ beta,
    const float* __restrict__ stats) {
    long total = (long)n * 256;
    float inv_n = 1.f / (float)n;
    for (long idx = (long)blockIdx.x * 256 + threadIdx.x; idx < total;
         idx += (long)gridDim.x * 256) {
        int col = (int)(idx & 255);
        float mean = stats[col] * inv_n;
        float var = stats[256 + col] * inv_n - mean * mean;
        float sc = rsqrtf(var + BN_EPS) * gamma[col];
        float v = (x[idx] - mean) * sc + beta[col];
        if (TANH) v = tanhf(v);
        y[idx] = v;
    }
}

// ---------------------------------------------------------------------------
// Quaternion vec-vec multiplication
// ---------------------------------------------------------------------------
__global__ __launch_bounds__(256) void hr_kernel(
    const float* __restrict__ X, const float* __restrict__ R,
    const int* __restrict__ e1_idx, const int* __restrict__ r_idx,
    float* __restrict__ hr) {
    int idx = blockIdx.x * 256 + threadIdx.x;
    if (idx >= BATCH * 64) return;
    int b = idx >> 6, s = idx & 63;
    const float* h = X + (long)e1_idx[b] * 256;
    const float* p = R + (long)r_idx[b] * 256;
    float qr = h[s], qi = h[64 + s], qj = h[128 + s], qk = h[192 + s];
    float pr = p[s], pi = p[64 + s], pj = p[128 + s], pk = p[192 + s];
    float inv = rsqrtf(pr * pr + pi * pi + pj * pj + pk * pk);
    pr *= inv; pi *= inv; pj *= inv; pk *= inv;
    float* o = hr + (long)b * 256 + s;
    o[0]   = qr * pr - qi * pi - qj * pj - qk * pk;
    o[64]  = qi * pr + qr * pi - qk * pj + qj * pk;
    o[128] = qj * pr + qk * pi + qr * pj - qi * pk;
    o[192] = qk * pr - qj * pi + qi * pj + qr * pk;
}

// ---------------------------------------------------------------------------
// Host-side orchestration
// ---------------------------------------------------------------------------
struct Csr {
    int* off;      // n+1
    int* cur;      // n (also used as histogram buffer)
    int* ccols;    // NEDGE
    float* cvals;  // NEDGE
};

struct Ws {
    float* supportBuf;  // (50500,256)
    float* aggA;        // (50500,256)
    float* aggB;        // (50000,256)
    float* XRcur;       // (50500,256)
    float* H256;        // (256,256)
    float* H512;        // (512,256)
    float* hr;          // (512,256)
    float* hrn;         // (512,256)
    float* stats;       // 512
    Csr adj;            // n_rows = N_ENTS
    Csr adjr;           // n_rows = N_ALL
};

static void build_csr(const int* rows, const int* cols, const float* vals,
                      int n_rows, const Csr& c, hipStream_t stream) {
    hipMemsetAsync(c.cur, 0, (size_t)n_rows * sizeof(int), stream);
    hist_kernel<<<(NEDGE + 255) / 256, 256, 0, stream>>>(rows, c.cur, NEDGE);
    exscan_kernel<<<1, 1024, 0, stream>>>(c.cur, n_rows, c.off);
    hipMemcpyAsync(c.cur, c.off, (size_t)n_rows * sizeof(int),
                   hipMemcpyDeviceToDevice, stream);
    scatter_kernel<<<(NEDGE + 255) / 256, 256, 0, stream>>>(
        rows, cols, vals, c.cur, c.ccols, c.cvals, NEDGE);
}

static void run_bn(float* buf, float* outbuf, int n, const float* gamma,
                   const float* beta, bool do_tanh, const Ws& w,
                   hipStream_t stream) {
    hipMemsetAsync(w.stats, 0, 512 * sizeof(float), stream);
    bn_stats_kernel<<<(n + 255) / 256, 256, 0, stream>>>(buf, n, w.stats);
    long total = (long)n * 256;
    int blocks = (int)((total + 255) / 256);
    if (blocks > 2048) blocks = 2048;
    if (do_tanh)
        bn_apply_kernel<true><<<blocks, 256, 0, stream>>>(buf, outbuf, n, gamma, beta, w.stats);
    else
        bn_apply_kernel<false><<<blocks, 256, 0, stream>>>(buf, outbuf, n, gamma, beta, w.stats);
}

static void run_q4gnn(const float* Xin, int n, const Csr& c,
                      const float* W, const float* gamma,
                      const float* beta, float* agg, const Ws& w,
                      hipStream_t stream) {
    build_hamilton_kernel<<<(4 * 64 * 256) / 256, 256, 0, stream>>>(W, w.H256, 64);
    dim3 g(2, (n + 127) / 128);
    gemm_nn_kernel<<<g, 256, 0, stream>>>(Xin, w.H256, w.supportBuf, n, 256, 256);
    int agg_blocks = (n * 64 + 255) / 256;
    csr_agg_kernel<<<agg_blocks, 256, 0, stream>>>(
        w.supportBuf, c.off, c.ccols, c.cvals, agg, n);
    run_bn(agg, agg, n, gamma, beta, true, w, stream);
}

static void run_score(const float* X, const float* R, const int* e1_idx,
                      const int* r_idx, const float* gamma, const float* beta,
                      float* out_l, const Ws& w, hipStream_t stream) {
    hr_kernel<<<(BATCH * 64) / 256, 256, 0, stream>>>(X, R, e1_idx, r_idx, w.hr);
    run_bn(w.hr, w.hrn, BATCH, gamma, beta, false, w, stream);
    dim3 g((N_ENTS + 127) / 128, BATCH / 128);
    gemm_nt_sig_kernel<<<g, 256, 0, stream>>>(w.hrn, X, out_l);
}

extern "C" void kernel_launch(void* const* d_in, const int* in_sizes, int n_in,
                              void* d_out, int out_size, void* d_ws, size_t ws_size,
                              hipStream_t stream) {
    const int*   e1_idx     = (const int*)d_in[0];
    const int*   r_idx      = (const int*)d_in[1];
    const float* emb        = (const float*)d_in[2];
    const float* gcn1_w     = (const float*)d_in[3];
    const float* gcn2_w     = (const float*)d_in[4];
    const float* gcn1_gamma = (const float*)d_in[5];
    const float* gcn1_beta  = (const float*)d_in[6];
    const float* gcn2_gamma = (const float*)d_in[7];
    const float* gcn2_beta  = (const float*)d_in[8];
    const float* lin_ents   = (const float*)d_in[9];
    const float* bn_s_gamma = (const float*)d_in[10];
    const float* bn_s_beta  = (const float*)d_in[11];
    const int*   adj_rows   = (const int*)d_in[12];
    const int*   adj_cols   = (const int*)d_in[13];
    const float* adj_vals   = (const float*)d_in[14];
    const int*   adjr_rows  = (const int*)d_in[15];
    const int*   adjr_cols  = (const int*)d_in[16];
    const float* adjr_vals  = (const float*)d_in[17];
    float* out = (float*)d_out;

    Ws w;
    float* f = (float*)d_ws;
    w.supportBuf = f; f += (long)N_ALL * EMB;
    w.aggA       = f; f += (long)N_ALL * EMB;
    w.aggB       = f; f += (long)N_ENTS * EMB;
    w.XRcur      = f; f += (long)N_ALL * EMB;
    w.H256       = f; f += 256 * 256;
    w.H512       = f; f += 512 * 256;
    w.hr         = f; f += BATCH * EMB;
    w.hrn        = f; f += BATCH * EMB;
    w.stats      = f; f += 512;
    int* ip = (int*)f;
    w.adj.off    = ip; ip += N_ENTS + 1;
    w.adj.cur    = ip; ip += N_ENTS;
    w.adj.ccols  = ip; ip += NEDGE;
    w.adjr.off   = ip; ip += N_ALL + 1;
    w.adjr.cur   = ip; ip += N_ALL;
    w.adjr.ccols = ip; ip += NEDGE;
    w.adj.cvals  = (float*)ip; ip += NEDGE;
    w.adjr.cvals = (float*)ip; ip += NEDGE;

    // Build both CSRs once; reused by both layers.
    build_csr(adj_rows, adj_cols, adj_vals, N_ENTS, w.adj, stream);
    build_csr(adjr_rows, adjr_cols, adjr_vals, N_ALL, w.adjr, stream);

    // score 0
    run_score(emb, emb + (long)N_ENTS * EMB, e1_idx, r_idx,
              bn_s_gamma, bn_s_beta, out, w, stream);

    for (int l = 0; l < 2; l++) {
        const float* XRptr = (l == 0) ? emb : w.XRcur;
        run_q4gnn(XRptr, N_ALL, w.adjr,
                  gcn2_w + (long)l * 64 * 256, gcn2_gamma + l * 256,
                  gcn2_beta + l * 256, w.aggA, w, stream);
        run_q4gnn(XRptr, N_ENTS, w.adj,
                  gcn1_w + (long)l * 64 * 256, gcn1_gamma + l * 256,
                  gcn1_beta + l * 256, w.aggB, w, stream);
        build_hamilton_kernel<<<(4 * 128 * 256) / 256, 256, 0, stream>>>(
            lin_ents + (long)l * 128 * 256, w.H512, 128);
        dim3 g(2, (N_ENTS + 127) / 128);
        gemm_lin_kernel<<<g, 256, 0, stream>>>(w.aggB, w.aggA, w.H512, w.XRcur, N_ENTS);
        hipMemcpyAsync(w.XRcur + (long)N_ENTS * EMB, w.aggA + (long)N_ENTS * EMB,
                       (size_t)N_RELS * EMB * sizeof(float),
                       hipMemcpyDeviceToDevice, stream);
        run_score(w.XRcur, w.XRcur + (long)N_ENTS * EMB, e1_idx, r_idx,
                  bn_s_gamma + (l + 1) * 256, bn_s_beta + (l + 1) * 256,
                  out + (long)(l + 1) * BATCH * N_ENTS, w, stream);
    }
}

// Round 4
// 2013.830 us; speedup vs baseline: 1.5551x; 1.5551x over previous
//
#include <hip/hip_runtime.h>
#include <math.h>

#define N_ENTS 50000
#define N_RELS 500
#define N_ALL  50500
#define EMB    256
#define NEDGE  400000
#define BATCH  512
#define BN_EPS 1e-5f

typedef unsigned short u16;
typedef unsigned int   u32;
typedef __attribute__((ext_vector_type(8))) short s16x8;  // 8 bf16 (4 VGPRs)
typedef __attribute__((ext_vector_type(4))) float f32x4;  // MFMA acc

// LDS row stride in u16 for 32-wide K tiles: 40 shorts = 80 B, multiple of
// 16 B (ds_read_b128 alignment) and 20-bank-quad stride => <=2-way (free)
// conflicts on fragment reads.
#define LSTR 40

// ---------------------------------------------------------------------------
// bf16 split helpers (RNE). x = hi + lo with |x-hi-lo| ~ 2^-17|x|.
// ---------------------------------------------------------------------------
__device__ __forceinline__ u16 f2b(float x) {
    u32 u = __float_as_uint(x);
    return (u16)((u + 0x7fffu + ((u >> 16) & 1u)) >> 16);
}
__device__ __forceinline__ float b2f(u16 h) {
    return __uint_as_float((u32)h << 16);
}

// Split fp32 array into bf16 hi/lo arrays. n4 = count of float4 groups.
__global__ __launch_bounds__(256) void split_kernel(
    const float* __restrict__ x, u16* __restrict__ hi, u16* __restrict__ lo,
    long n4) {
    long i = (long)blockIdx.x * 256 + threadIdx.x;
    if (i >= n4) return;
    float4 v = ((const float4*)x)[i];
    u16 h0 = f2b(v.x), h1 = f2b(v.y), h2 = f2b(v.z), h3 = f2b(v.w);
    u16 l0 = f2b(v.x - b2f(h0)), l1 = f2b(v.y - b2f(h1));
    u16 l2 = f2b(v.z - b2f(h2)), l3 = f2b(v.w - b2f(h3));
    uint2 hp, lp;
    hp.x = (u32)h0 | ((u32)h1 << 16); hp.y = (u32)h2 | ((u32)h3 << 16);
    lp.x = (u32)l0 | ((u32)l1 << 16); lp.y = (u32)l2 | ((u32)l3 << 16);
    ((uint2*)hi)[i] = hp;
    ((uint2*)lo)[i] = lp;
}

// ---------------------------------------------------------------------------
// Build TRANSPOSED hamilton HT[n][k] (N=256 rows, K=4P cols), pre-split bf16.
// HT[n][k] = sgn[a][c] * W[p*256 + comp[a][c]*64 + s], k=a*P+p, n=c*64+s.
// ---------------------------------------------------------------------------
__global__ __launch_bounds__(256) void build_ht_kernel(
    const float* __restrict__ W, u16* __restrict__ Hhi, u16* __restrict__ Hlo,
    int P) {
    int K4 = 4 * P;
    int idx = blockIdx.x * 256 + threadIdx.x;
    int total = 256 * K4;
    if (idx >= total) return;
    int n = idx / K4, k = idx - n * K4;
    int a = k / P, p = k - a * P;
    int c = n >> 6, s = n & 63;
    const int  comp[4][4] = {{0,1,2,3},{1,0,3,2},{2,3,0,1},{3,2,1,0}};
    const float sgn[4][4] = {{1.f,1.f,1.f,1.f},
                             {-1.f,1.f,1.f,-1.f},
                             {-1.f,-1.f,1.f,1.f},
                             {-1.f,1.f,-1.f,1.f}};
    float v = sgn[a][c] * W[p * 256 + comp[a][c] * 64 + s];
    u16 h = f2b(v);
    Hhi[idx] = h;
    Hlo[idx] = f2b(v - b2f(h));
}

// ---------------------------------------------------------------------------
// MFMA GEMM core (BT form): C[m][n] = sum_k A[m][k]*Bt[n][k].
// Block 256 thr = 4 waves (2x2 of 64x64), tile 128x128, K-step 32.
// mfma_f32_16x16x32_bf16; split-bf16: 3 MFMAs per fragment pair.
// Fragment layouts (gfx950, m89-verified D): A lane l: row=l&15, k=(l>>4)*8+j;
// Bt lane l: n=l&15, k=(l>>4)*8+j; D lane l reg r: row=(l>>4)*4+r, col=l&15.
// ---------------------------------------------------------------------------
__device__ __forceinline__ void stage_split(
    const u16* __restrict__ Shi, const u16* __restrict__ Slo,
    long row0, int rows_left, int K, int k0,
    u16* __restrict__ Lh, u16* __restrict__ Ll, int tid) {
#pragma unroll
    for (int p = 0; p < 2; p++) {
        int idx = tid + p * 256;
        int r = idx >> 2, c = idx & 3;
        uint4 vh = make_uint4(0, 0, 0, 0), vl = make_uint4(0, 0, 0, 0);
        if (r < rows_left) {
            long base = (row0 + r) * (long)K + k0 + c * 8;
            vh = *(const uint4*)&Shi[base];
            vl = *(const uint4*)&Slo[base];
        }
        *(uint4*)&Lh[r * LSTR + c * 8] = vh;
        *(uint4*)&Ll[r * LSTR + c * 8] = vl;
    }
}

__device__ __forceinline__ void mfma_tile(
    const u16* __restrict__ Ah, const u16* __restrict__ Al,
    const u16* __restrict__ Bh, const u16* __restrict__ Bl,
    int wm, int wn, int lane, f32x4 acc[4][4]) {
    int lr = lane & 15, lkg = lane >> 4;
    s16x8 ah[4], al[4];
#pragma unroll
    for (int fm = 0; fm < 4; fm++) {
        int off = (wm + fm * 16 + lr) * LSTR + lkg * 8;
        ah[fm] = *(const s16x8*)&Ah[off];
        al[fm] = *(const s16x8*)&Al[off];
    }
#pragma unroll
    for (int fn = 0; fn < 4; fn++) {
        int off = (wn + fn * 16 + lr) * LSTR + lkg * 8;
        s16x8 bh = *(const s16x8*)&Bh[off];
        s16x8 bl = *(const s16x8*)&Bl[off];
#pragma unroll
        for (int fm = 0; fm < 4; fm++) {
            acc[fm][fn] = __builtin_amdgcn_mfma_f32_16x16x32_bf16(
                ah[fm], bh, acc[fm][fn], 0, 0, 0);
            acc[fm][fn] = __builtin_amdgcn_mfma_f32_16x16x32_bf16(
                ah[fm], bl, acc[fm][fn], 0, 0, 0);
            acc[fm][fn] = __builtin_amdgcn_mfma_f32_16x16x32_bf16(
                al[fm], bh, acc[fm][fn], 0, 0, 0);
        }
    }
}

// Generic BT GEMM (used for support: A=XR split, Bt=HT split, N=256, K=256).
__global__ __launch_bounds__(256) void mfma_gemm_bt_kernel(
    const u16* __restrict__ Ahi, const u16* __restrict__ Alo,
    const u16* __restrict__ Bhi, const u16* __restrict__ Blo,
    float* __restrict__ C, int M, int N, int K) {
    __shared__ u16 Ah[128 * LSTR], Al[128 * LSTR];
    __shared__ u16 Bh[128 * LSTR], Bl[128 * LSTR];
    int tid = threadIdx.x, lane = tid & 63, wid = tid >> 6;
    int wm = (wid >> 1) * 64, wn = (wid & 1) * 64;
    long bm0 = (long)blockIdx.y * 128, bn0 = (long)blockIdx.x * 128;
    int rA = (int)(((long)M - bm0 < 128) ? (long)M - bm0 : 128);
    int rB = (int)(((long)N - bn0 < 128) ? (long)N - bn0 : 128);
    f32x4 acc[4][4] = {};
    for (int k0 = 0; k0 < K; k0 += 32) {
        if (k0) __syncthreads();
        stage_split(Ahi, Alo, bm0, rA, K, k0, Ah, Al, tid);
        stage_split(Bhi, Blo, bn0, rB, K, k0, Bh, Bl, tid);
        __syncthreads();
        mfma_tile(Ah, Al, Bh, Bl, wm, wn, lane, acc);
    }
    int lr = lane & 15, lq = lane >> 4;
#pragma unroll
    for (int fm = 0; fm < 4; fm++) {
#pragma unroll
        for (int r = 0; r < 4; r++) {
            long row = bm0 + wm + fm * 16 + lq * 4 + r;
            if (row < M) {
#pragma unroll
                for (int fn = 0; fn < 4; fn++) {
                    long col = bn0 + wn + fn * 16 + lr;
                    if (col < N) C[row * N + col] = acc[fm][fn][r];
                }
            }
        }
    }
}

// Score GEMM: A=hrn split (512xK=256), Bt=X split (50000x256), sigmoid out.
__global__ __launch_bounds__(256) void mfma_score_kernel(
    const u16* __restrict__ Ahi, const u16* __restrict__ Alo,
    const u16* __restrict__ Bhi, const u16* __restrict__ Blo,
    float* __restrict__ out) {
    __shared__ u16 Ah[128 * LSTR], Al[128 * LSTR];
    __shared__ u16 Bh[128 * LSTR], Bl[128 * LSTR];
    int tid = threadIdx.x, lane = tid & 63, wid = tid >> 6;
    int wm = (wid >> 1) * 64, wn = (wid & 1) * 64;
    long bm0 = (long)blockIdx.y * 128, bn0 = (long)blockIdx.x * 128;
    int rB = (int)(((long)N_ENTS - bn0 < 128) ? (long)N_ENTS - bn0 : 128);
    f32x4 acc[4][4] = {};
    for (int k0 = 0; k0 < 256; k0 += 32) {
        if (k0) __syncthreads();
        stage_split(Ahi, Alo, bm0, 128, 256, k0, Ah, Al, tid);
        stage_split(Bhi, Blo, bn0, rB, 256, k0, Bh, Bl, tid);
        __syncthreads();
        mfma_tile(Ah, Al, Bh, Bl, wm, wn, lane, acc);
    }
    int lr = lane & 15, lq = lane >> 4;
#pragma unroll
    for (int fm = 0; fm < 4; fm++) {
#pragma unroll
        for (int r = 0; r < 4; r++) {
            long row = bm0 + wm + fm * 16 + lq * 4 + r;  // < 512 always
#pragma unroll
            for (int fn = 0; fn < 4; fn++) {
                long col = bn0 + wn + fn * 16 + lr;
                if (col < N_ENTS) {
                    float v = acc[fm][fn][r];
                    out[row * N_ENTS + col] = 1.f / (1.f + __expf(-v));
                }
            }
        }
    }
}

// Lin GEMM: C[50000,256] = Xcat[50000,512] @ H512; A-side converts fp32
// interleave (Xef/Xrf) to split bf16 in-staging; Bt = HT512 split (256x512).
__device__ __forceinline__ float4 lin_a_load(const float* __restrict__ Xef,
                                             const float* __restrict__ Xrf,
                                             int gm, int kk, int M) {
    // kk multiple of 4; a float4 never crosses a 64-chunk boundary.
    int chunk = kk >> 6, s = kk & 63;
    const float* src = (chunk & 1) ? Xrf : Xef;
    float4 v = make_float4(0.f, 0.f, 0.f, 0.f);
    if (gm < M) v = *(const float4*)&src[(long)gm * 256 + (chunk >> 1) * 64 + s];
    return v;
}

__global__ __launch_bounds__(256) void mfma_lin_kernel(
    const float* __restrict__ Xef, const float* __restrict__ Xrf,
    const u16* __restrict__ Bhi, const u16* __restrict__ Blo,
    float* __restrict__ C, int M) {
    __shared__ u16 Ah[128 * LSTR], Al[128 * LSTR];
    __shared__ u16 Bh[128 * LSTR], Bl[128 * LSTR];
    int tid = threadIdx.x, lane = tid & 63, wid = tid >> 6;
    int wm = (wid >> 1) * 64, wn = (wid & 1) * 64;
    int bm0 = blockIdx.y * 128;
    long bn0 = (long)blockIdx.x * 128;  // N=256: bn0 in {0,128}
    f32x4 acc[4][4] = {};
    for (int k0 = 0; k0 < 512; k0 += 32) {
        if (k0) __syncthreads();
        // A: fp32 interleave -> split bf16 -> LDS.
#pragma unroll
        for (int p = 0; p < 4; p++) {
            int idx = tid + p * 256;
            int r = idx >> 3, c4 = idx & 7;
            float4 v = lin_a_load(Xef, Xrf, bm0 + r, k0 + c4 * 4, M);
            u16 h0 = f2b(v.x), h1 = f2b(v.y), h2 = f2b(v.z), h3 = f2b(v.w);
            u16 l0 = f2b(v.x - b2f(h0)), l1 = f2b(v.y - b2f(h1));
            u16 l2 = f2b(v.z - b2f(h2)), l3 = f2b(v.w - b2f(h3));
            uint2 hp, lp;
            hp.x = (u32)h0 | ((u32)h1 << 16); hp.y = (u32)h2 | ((u32)h3 << 16);
            lp.x = (u32)l0 | ((u32)l1 << 16); lp.y = (u32)l2 | ((u32)l3 << 16);
            *(uint2*)&Ah[r * LSTR + c4 * 4] = hp;
            *(uint2*)&Al[r * LSTR + c4 * 4] = lp;
        }
        stage_split(Bhi, Blo, bn0, 128, 512, k0, Bh, Bl, tid);
        __syncthreads();
        mfma_tile(Ah, Al, Bh, Bl, wm, wn, lane, acc);
    }
    int lr = lane & 15, lq = lane >> 4;
#pragma unroll
    for (int fm = 0; fm < 4; fm++) {
#pragma unroll
        for (int r = 0; r < 4; r++) {
            long row = (long)bm0 + wm + fm * 16 + lq * 4 + r;
            if (row < M) {
#pragma unroll
                for (int fn = 0; fn < 4; fn++) {
                    long col = bn0 + wn + fn * 16 + lr;
                    C[row * 256 + col] = acc[fm][fn][r];
                }
            }
        }
    }
}

// ---------------------------------------------------------------------------
// CSR build: histogram, single-block exclusive scan, ticket scatter.
// ---------------------------------------------------------------------------
__global__ __launch_bounds__(256) void hist_kernel(
    const int* __restrict__ rows, int* __restrict__ cnt, int n_edges) {
    int e = blockIdx.x * 256 + threadIdx.x;
    if (e < n_edges) atomicAdd(&cnt[rows[e]], 1);
}

__global__ __launch_bounds__(1024) void exscan_kernel(
    const int* __restrict__ cnt, int n, int* __restrict__ off) {
    __shared__ int part[1024];
    int t = threadIdx.x;
    int chunk = (n + 1023) / 1024;
    int lo = t * chunk;
    int hi = lo + chunk; if (hi > n) hi = n;
    int s = 0;
    for (int i = lo; i < hi; i++) s += cnt[i];
    part[t] = s;
    __syncthreads();
    for (int d = 1; d < 1024; d <<= 1) {
        int v = (t >= d) ? part[t - d] : 0;
        __syncthreads();
        part[t] += v;
        __syncthreads();
    }
    int base = (t == 0) ? 0 : part[t - 1];
    for (int i = lo; i < hi; i++) {
        off[i] = base;
        base += cnt[i];
    }
    if (hi >= n) off[n] = base;
}

__global__ __launch_bounds__(256) void scatter_kernel(
    const int* __restrict__ rows, const int* __restrict__ cols,
    const float* __restrict__ vals, int* __restrict__ cursor,
    int* __restrict__ csr_cols, float* __restrict__ csr_vals, int n_edges) {
    int e = blockIdx.x * 256 + threadIdx.x;
    if (e >= n_edges) return;
    int r = rows[e];
    int p = atomicAdd(&cursor[r], 1);
    csr_cols[p] = cols[e];
    csr_vals[p] = vals[e];
}

// ---------------------------------------------------------------------------
// CSR aggregation: one 64-lane wave per row, lane owns 4 consecutive floats.
// ---------------------------------------------------------------------------
__global__ __launch_bounds__(256) void csr_agg_kernel(
    const float* __restrict__ support, const int* __restrict__ off,
    const int* __restrict__ ccols, const float* __restrict__ cvals,
    float* __restrict__ agg, int n_rows) {
    int gid = blockIdx.x * 256 + threadIdx.x;
    int row = gid >> 6;
    int lane = gid & 63;
    if (row >= n_rows) return;
    int beg = off[row], end = off[row + 1];
    float4 acc = {0.f, 0.f, 0.f, 0.f};
    for (int e = beg; e < end; e++) {
        int c = ccols[e];
        float v = cvals[e];
        const float4 s = *(const float4*)(support + (long)c * 256 + lane * 4);
        acc.x = fmaf(v, s.x, acc.x);
        acc.y = fmaf(v, s.y, acc.y);
        acc.z = fmaf(v, s.z, acc.z);
        acc.w = fmaf(v, s.w, acc.w);
    }
    *(float4*)(agg + (long)row * 256 + lane * 4) = acc;
}

// ---------------------------------------------------------------------------
// Column stats + BN apply (+ optional tanh)
// ---------------------------------------------------------------------------
__global__ __launch_bounds__(256) void bn_stats_kernel(
    const float* __restrict__ x, int n, float* __restrict__ stats) {
    int col = threadIdx.x;
    int r0 = blockIdx.x * 256;
    int r1 = r0 + 256;
    if (r1 > n) r1 = n;
    float s = 0.f, sq = 0.f;
    for (int r = r0; r < r1; r++) {
        float v = x[(long)r * 256 + col];
        s += v;
        sq += v * v;
    }
    atomicAdd(&stats[col], s);
    atomicAdd(&stats[256 + col], sq);
}

template <bool TANH>
__global__ __launch_bounds__(256) void bn_apply_kernel(
    const float* __restrict__ x, float* __restrict__ y, int n,
    const float* __restrict__ gamma, const float* __restrict__ beta,
    const float* __restrict__ stats) {
    long total = (long)n * 256;
    float inv_n = 1.f / (float)n;
    for (long idx = (long)blockIdx.x * 256 + threadIdx.x; idx < total;
         idx += (long)gridDim.x * 256) {
        int col = (int)(idx & 255);
        float mean = stats[col] * inv_n;
        float var = stats[256 + col] * inv_n - mean * mean;
        float sc = rsqrtf(var + BN_EPS) * gamma[col];
        float v = (x[idx] - mean) * sc + beta[col];
        if (TANH) v = tanhf(v);
        y[idx] = v;
    }
}

// ---------------------------------------------------------------------------
// Quaternion vec-vec multiplication
// ---------------------------------------------------------------------------
__global__ __launch_bounds__(256) void hr_kernel(
    const float* __restrict__ X, const float* __restrict__ R,
    const int* __restrict__ e1_idx, const int* __restrict__ r_idx,
    float* __restrict__ hr) {
    int idx = blockIdx.x * 256 + threadIdx.x;
    if (idx >= BATCH * 64) return;
    int b = idx >> 6, s = idx & 63;
    const float* h = X + (long)e1_idx[b] * 256;
    const float* p = R + (long)r_idx[b] * 256;
    float qr = h[s], qi = h[64 + s], qj = h[128 + s], qk = h[192 + s];
    float pr = p[s], pi = p[64 + s], pj = p[128 + s], pk = p[192 + s];
    float inv = rsqrtf(pr * pr + pi * pi + pj * pj + pk * pk);
    pr *= inv; pi *= inv; pj *= inv; pk *= inv;
    float* o = hr + (long)b * 256 + s;
    o[0]   = qr * pr - qi * pi - qj * pj - qk * pk;
    o[64]  = qi * pr + qr * pi - qk * pj + qj * pk;
    o[128] = qj * pr + qk * pi + qr * pj - qi * pk;
    o[192] = qk * pr - qj * pi + qi * pj + qr * pk;
}

// ---------------------------------------------------------------------------
// Host-side orchestration
// ---------------------------------------------------------------------------
struct Csr {
    int* off;
    int* cur;
    int* ccols;
    float* cvals;
};

struct Ws {
    float* supportBuf;  // (50500,256)
    float* aggA;        // (50500,256)
    float* aggB;        // (50000,256)
    float* XRcur;       // (50500,256)
    float* hr;          // (512,256)
    float* hrn;         // (512,256)
    float* stats;       // 512
    u16* xr_hi;         // (50500,256) bf16 split of current XR
    u16* xr_lo;
    u16* hrn_hi;        // (512,256)
    u16* hrn_lo;
    u16* ht_hi;         // (256,512) max
    u16* ht_lo;
    Csr adj;
    Csr adjr;
};

static void build_csr(const int* rows, const int* cols, const float* vals,
                      int n_rows, const Csr& c, hipStream_t stream) {
    hipMemsetAsync(c.cur, 0, (size_t)n_rows * sizeof(int), stream);
    hist_kernel<<<(NEDGE + 255) / 256, 256, 0, stream>>>(rows, c.cur, NEDGE);
    exscan_kernel<<<1, 1024, 0, stream>>>(c.cur, n_rows, c.off);
    hipMemcpyAsync(c.cur, c.off, (size_t)n_rows * sizeof(int),
                   hipMemcpyDeviceToDevice, stream);
    scatter_kernel<<<(NEDGE + 255) / 256, 256, 0, stream>>>(
        rows, cols, vals, c.cur, c.ccols, c.cvals, NEDGE);
}

static void run_bn(float* buf, float* outbuf, int n, const float* gamma,
                   const float* beta, bool do_tanh, const Ws& w,
                   hipStream_t stream) {
    hipMemsetAsync(w.stats, 0, 512 * sizeof(float), stream);
    bn_stats_kernel<<<(n + 255) / 256, 256, 0, stream>>>(buf, n, w.stats);
    long total = (long)n * 256;
    int blocks = (int)((total + 255) / 256);
    if (blocks > 2048) blocks = 2048;
    if (do_tanh)
        bn_apply_kernel<true><<<blocks, 256, 0, stream>>>(buf, outbuf, n, gamma, beta, w.stats);
    else
        bn_apply_kernel<false><<<blocks, 256, 0, stream>>>(buf, outbuf, n, gamma, beta, w.stats);
}

static void run_split(const float* x, u16* hi, u16* lo, long n,
                      hipStream_t stream) {
    long n4 = n / 4;
    split_kernel<<<(int)((n4 + 255) / 256), 256, 0, stream>>>(x, hi, lo, n4);
}

static void run_q4gnn(int n, const Csr& c, const float* W, const float* gamma,
                      const float* beta, float* agg, const Ws& w,
                      hipStream_t stream) {
    build_ht_kernel<<<(256 * 256) / 256, 256, 0, stream>>>(W, w.ht_hi, w.ht_lo, 64);
    dim3 g(2, (n + 127) / 128);
    mfma_gemm_bt_kernel<<<g, 256, 0, stream>>>(
        w.xr_hi, w.xr_lo, w.ht_hi, w.ht_lo, w.supportBuf, n, 256, 256);
    int agg_blocks = (n * 64 + 255) / 256;
    csr_agg_kernel<<<agg_blocks, 256, 0, stream>>>(
        w.supportBuf, c.off, c.ccols, c.cvals, agg, n);
    run_bn(agg, agg, n, gamma, beta, true, w, stream);
}

static void run_score(const float* X, const float* R, const int* e1_idx,
                      const int* r_idx, const float* gamma, const float* beta,
                      float* out_l, const Ws& w, hipStream_t stream) {
    hr_kernel<<<(BATCH * 64) / 256, 256, 0, stream>>>(X, R, e1_idx, r_idx, w.hr);
    run_bn(w.hr, w.hrn, BATCH, gamma, beta, false, w, stream);
    run_split(w.hrn, w.hrn_hi, w.hrn_lo, (long)BATCH * EMB, stream);
    dim3 g((N_ENTS + 127) / 128, BATCH / 128);
    mfma_score_kernel<<<g, 256, 0, stream>>>(
        w.hrn_hi, w.hrn_lo, w.xr_hi, w.xr_lo, out_l);
}

extern "C" void kernel_launch(void* const* d_in, const int* in_sizes, int n_in,
                              void* d_out, int out_size, void* d_ws, size_t ws_size,
                              hipStream_t stream) {
    const int*   e1_idx     = (const int*)d_in[0];
    const int*   r_idx      = (const int*)d_in[1];
    const float* emb        = (const float*)d_in[2];
    const float* gcn1_w     = (const float*)d_in[3];
    const float* gcn2_w     = (const float*)d_in[4];
    const float* gcn1_gamma = (const float*)d_in[5];
    const float* gcn1_beta  = (const float*)d_in[6];
    const float* gcn2_gamma = (const float*)d_in[7];
    const float* gcn2_beta  = (const float*)d_in[8];
    const float* lin_ents   = (const float*)d_in[9];
    const float* bn_s_gamma = (const float*)d_in[10];
    const float* bn_s_beta  = (const float*)d_in[11];
    const int*   adj_rows   = (const int*)d_in[12];
    const int*   adj_cols   = (const int*)d_in[13];
    const float* adj_vals   = (const float*)d_in[14];
    const int*   adjr_rows  = (const int*)d_in[15];
    const int*   adjr_cols  = (const int*)d_in[16];
    const float* adjr_vals  = (const float*)d_in[17];
    float* out = (float*)d_out;

    Ws w;
    float* f = (float*)d_ws;
    w.supportBuf = f; f += (long)N_ALL * EMB;
    w.aggA       = f; f += (long)N_ALL * EMB;
    w.aggB       = f; f += (long)N_ENTS * EMB;
    w.XRcur      = f; f += (long)N_ALL * EMB;
    w.hr         = f; f += BATCH * EMB;
    w.hrn        = f; f += BATCH * EMB;
    w.stats      = f; f += 512;
    w.xr_hi  = (u16*)f; f += (long)N_ALL * EMB / 2;
    w.xr_lo  = (u16*)f; f += (long)N_ALL * EMB / 2;
    w.hrn_hi = (u16*)f; f += BATCH * EMB / 2;
    w.hrn_lo = (u16*)f; f += BATCH * EMB / 2;
    w.ht_hi  = (u16*)f; f += 256 * 512 / 2;
    w.ht_lo  = (u16*)f; f += 256 * 512 / 2;
    int* ip = (int*)f;
    w.adj.off    = ip; ip += N_ENTS + 1;
    w.adj.cur    = ip; ip += N_ENTS;
    w.adj.ccols  = ip; ip += NEDGE;
    w.adjr.off   = ip; ip += N_ALL + 1;
    w.adjr.cur   = ip; ip += N_ALL;
    w.adjr.ccols = ip; ip += NEDGE;
    w.adj.cvals  = (float*)ip; ip += NEDGE;
    w.adjr.cvals = (float*)ip; ip += NEDGE;

    // Build both CSRs once; reused by both layers.
    build_csr(adj_rows, adj_cols, adj_vals, N_ENTS, w.adj, stream);
    build_csr(adjr_rows, adjr_cols, adjr_vals, N_ALL, w.adjr, stream);

    // Split embeddings (entities+rels) once; used by score0 and layer-0 supports.
    run_split(emb, w.xr_hi, w.xr_lo, (long)N_ALL * EMB, stream);

    // score 0
    run_score(emb, emb + (long)N_ENTS * EMB, e1_idx, r_idx,
              bn_s_gamma, bn_s_beta, out, w, stream);

    for (int l = 0; l < 2; l++) {
        const float* XRptr = (l == 0) ? emb : w.XRcur;
        run_q4gnn(N_ALL, w.adjr, gcn2_w + (long)l * 64 * 256,
                  gcn2_gamma + l * 256, gcn2_beta + l * 256, w.aggA, w, stream);
        run_q4gnn(N_ENTS, w.adj, gcn1_w + (long)l * 64 * 256,
                  gcn1_gamma + l * 256, gcn1_beta + l * 256, w.aggB, w, stream);
        build_ht_kernel<<<(256 * 512) / 256, 256, 0, stream>>>(
            lin_ents + (long)l * 128 * 256, w.ht_hi, w.ht_lo, 128);
        dim3 g(2, (N_ENTS + 127) / 128);
        mfma_lin_kernel<<<g, 256, 0, stream>>>(
            w.aggB, w.aggA, w.ht_hi, w.ht_lo, w.XRcur, N_ENTS);
        hipMemcpyAsync(w.XRcur + (long)N_ENTS * EMB, w.aggA + (long)N_ENTS * EMB,
                       (size_t)N_RELS * EMB * sizeof(float),
                       hipMemcpyDeviceToDevice, stream);
        // Re-split current XR: feeds score(l+1) X and next layer's supports.
        run_split(w.XRcur, w.xr_hi, w.xr_lo, (long)N_ALL * EMB, stream);
        run_score(w.XRcur, w.XRcur + (long)N_ENTS * EMB, e1_idx, r_idx,
                  bn_s_gamma + (l + 1) * 256, bn_s_beta + (l + 1) * 256,
                  out + (long)(l + 1) * BATCH * N_ENTS, w, stream);
        (void)XRptr;
    }
}

// Round 6
// 1893.971 us; speedup vs baseline: 1.6535x; 1.0633x over previous
//
#include <hip/hip_runtime.h>
#include <math.h>

#define N_ENTS 50000
#define N_RELS 500
#define N_ALL  50500
#define EMB    256
#define NEDGE  400000
#define BATCH  512
#define BN_EPS 1e-5f

typedef unsigned short u16;
typedef unsigned int   u32;
typedef __attribute__((ext_vector_type(8))) short s16x8;  // 8 bf16 (4 VGPRs)
typedef __attribute__((ext_vector_type(4))) float f32x4;  // MFMA acc

// LDS row stride in u16 for 32-wide K tiles: 40 shorts = 80 B, 16B-aligned
// chunks, 20-bank-quad stride => <=2-way (free) conflicts on fragment reads.
#define LSTR 40

// ---------------------------------------------------------------------------
// bf16 split helpers (RNE). x = hi + lo with |x-hi-lo| ~ 2^-17|x|.
// ---------------------------------------------------------------------------
__device__ __forceinline__ u16 f2b(float x) {
    u32 u = __float_as_uint(x);
    return (u16)((u + 0x7fffu + ((u >> 16) & 1u)) >> 16);
}
__device__ __forceinline__ float b2f(u16 h) {
    return __uint_as_float((u32)h << 16);
}

// Split fp32 array into bf16 hi/lo arrays. n4 = count of float4 groups.
__global__ __launch_bounds__(256) void split_kernel(
    const float* __restrict__ x, u16* __restrict__ hi, u16* __restrict__ lo,
    long n4) {
    long i = (long)blockIdx.x * 256 + threadIdx.x;
    if (i >= n4) return;
    float4 v = ((const float4*)x)[i];
    u16 h0 = f2b(v.x), h1 = f2b(v.y), h2 = f2b(v.z), h3 = f2b(v.w);
    u16 l0 = f2b(v.x - b2f(h0)), l1 = f2b(v.y - b2f(h1));
    u16 l2 = f2b(v.z - b2f(h2)), l3 = f2b(v.w - b2f(h3));
    uint2 hp, lp;
    hp.x = (u32)h0 | ((u32)h1 << 16); hp.y = (u32)h2 | ((u32)h3 << 16);
    lp.x = (u32)l0 | ((u32)l1 << 16); lp.y = (u32)l2 | ((u32)l3 << 16);
    ((uint2*)hi)[i] = hp;
    ((uint2*)lo)[i] = lp;
}

// ---------------------------------------------------------------------------
// Build TRANSPOSED hamilton HT[n][k] (256 rows, K=4P cols), pre-split bf16.
// ---------------------------------------------------------------------------
__global__ __launch_bounds__(256) void build_ht_kernel(
    const float* __restrict__ W, u16* __restrict__ Hhi, u16* __restrict__ Hlo,
    int P) {
    int K4 = 4 * P;
    int idx = blockIdx.x * 256 + threadIdx.x;
    int total = 256 * K4;
    if (idx >= total) return;
    int n = idx / K4, k = idx - n * K4;
    int a = k / P, p = k - a * P;
    int c = n >> 6, s = n & 63;
    const int  comp[4][4] = {{0,1,2,3},{1,0,3,2},{2,3,0,1},{3,2,1,0}};
    const float sgn[4][4] = {{1.f,1.f,1.f,1.f},
                             {-1.f,1.f,1.f,-1.f},
                             {-1.f,-1.f,1.f,1.f},
                             {-1.f,1.f,-1.f,1.f}};
    float v = sgn[a][c] * W[p * 256 + comp[a][c] * 64 + s];
    u16 h = f2b(v);
    Hhi[idx] = h;
    Hlo[idx] = f2b(v - b2f(h));
}

// ---------------------------------------------------------------------------
// MFMA GEMM core (BT form): C[m][n] = sum_k A[m][k]*Bt[n][k].
// Block 256 thr = 4 waves as 2Mx2N, tile 128x256, wave tile 64x128.
// K-step 32, mfma_f32_16x16x32_bf16, split-bf16 3-term.
// Per wave/K-step: 96 MFMA vs 24 ds_read_b128 (4:1) — less LDS per FLOP
// than the 64x64-wave variant (3:1) since LDS pipe is the bottleneck.
// ---------------------------------------------------------------------------
template <int ROWS>
__device__ __forceinline__ void stage_rows(
    const u16* __restrict__ Shi, const u16* __restrict__ Slo,
    long row0, int rows_left, int K, int k0,
    u16* __restrict__ Lh, u16* __restrict__ Ll, int tid) {
#pragma unroll
    for (int p = 0; p < ROWS / 64; p++) {
        int idx = tid + p * 256;
        int r = idx >> 2, c = idx & 3;
        uint4 vh = make_uint4(0, 0, 0, 0), vl = make_uint4(0, 0, 0, 0);
        if (r < rows_left) {
            long base = (row0 + r) * (long)K + k0 + c * 8;
            vh = *(const uint4*)&Shi[base];
            vl = *(const uint4*)&Slo[base];
        }
        *(uint4*)&Lh[r * LSTR + c * 8] = vh;
        *(uint4*)&Ll[r * LSTR + c * 8] = vl;
    }
}

__device__ __forceinline__ void mfma_tile256(
    const u16* __restrict__ Ah, const u16* __restrict__ Al,
    const u16* __restrict__ Bh, const u16* __restrict__ Bl,
    int wm, int wn, int lane, f32x4 acc[4][8]) {
    int lr = lane & 15, kg = lane >> 4;
    s16x8 ah[4], al[4];
#pragma unroll
    for (int fm = 0; fm < 4; fm++) {
        int off = (wm + fm * 16 + lr) * LSTR + kg * 8;
        ah[fm] = *(const s16x8*)&Ah[off];
        al[fm] = *(const s16x8*)&Al[off];
    }
#pragma unroll
    for (int fn = 0; fn < 8; fn++) {
        int off = (wn + fn * 16 + lr) * LSTR + kg * 8;
        s16x8 bh = *(const s16x8*)&Bh[off];
        s16x8 bl = *(const s16x8*)&Bl[off];
#pragma unroll
        for (int fm = 0; fm < 4; fm++) {
            acc[fm][fn] = __builtin_amdgcn_mfma_f32_16x16x32_bf16(
                ah[fm], bh, acc[fm][fn], 0, 0, 0);
            acc[fm][fn] = __builtin_amdgcn_mfma_f32_16x16x32_bf16(
                ah[fm], bl, acc[fm][fn], 0, 0, 0);
            acc[fm][fn] = __builtin_amdgcn_mfma_f32_16x16x32_bf16(
                al[fm], bh, acc[fm][fn], 0, 0, 0);
        }
    }
}

// Generic BT GEMM (support: A=XR split, Bt=HT split, N=256 => gridDim.x=1).
__global__ __launch_bounds__(256, 2) void mfma_gemm_bt_kernel(
    const u16* __restrict__ Ahi, const u16* __restrict__ Alo,
    const u16* __restrict__ Bhi, const u16* __restrict__ Blo,
    float* __restrict__ C, int M, int N, int K) {
    __shared__ u16 Ah[128 * LSTR], Al[128 * LSTR];
    __shared__ u16 Bh[256 * LSTR], Bl[256 * LSTR];
    int tid = threadIdx.x, lane = tid & 63, wid = tid >> 6;
    int wm = (wid >> 1) * 64, wn = (wid & 1) * 128;
    long bm0 = (long)blockIdx.y * 128, bn0 = (long)blockIdx.x * 256;
    int rA = (int)(((long)M - bm0 < 128) ? (long)M - bm0 : 128);
    int rB = (int)(((long)N - bn0 < 256) ? (long)N - bn0 : 256);
    f32x4 acc[4][8] = {};
    for (int k0 = 0; k0 < K; k0 += 32) {
        if (k0) __syncthreads();
        stage_rows<128>(Ahi, Alo, bm0, rA, K, k0, Ah, Al, tid);
        stage_rows<256>(Bhi, Blo, bn0, rB, K, k0, Bh, Bl, tid);
        __syncthreads();
        mfma_tile256(Ah, Al, Bh, Bl, wm, wn, lane, acc);
    }
    int lr = lane & 15, lq = lane >> 4;
#pragma unroll
    for (int fm = 0; fm < 4; fm++) {
#pragma unroll
        for (int r = 0; r < 4; r++) {
            long row = bm0 + wm + fm * 16 + lq * 4 + r;
            if (row < M) {
#pragma unroll
                for (int fn = 0; fn < 8; fn++) {
                    long col = bn0 + wn + fn * 16 + lr;
                    if (col < N) C[row * N + col] = acc[fm][fn][r];
                }
            }
        }
    }
}

// Score GEMM: A=hrn split (512x256), Bt=X split (50000x256), sigmoid out.
__global__ __launch_bounds__(256, 2) void mfma_score_kernel(
    const u16* __restrict__ Ahi, const u16* __restrict__ Alo,
    const u16* __restrict__ Bhi, const u16* __restrict__ Blo,
    float* __restrict__ out) {
    __shared__ u16 Ah[128 * LSTR], Al[128 * LSTR];
    __shared__ u16 Bh[256 * LSTR], Bl[256 * LSTR];
    int tid = threadIdx.x, lane = tid & 63, wid = tid >> 6;
    int wm = (wid >> 1) * 64, wn = (wid & 1) * 128;
    long bm0 = (long)blockIdx.y * 128, bn0 = (long)blockIdx.x * 256;
    int rB = (int)(((long)N_ENTS - bn0 < 256) ? (long)N_ENTS - bn0 : 256);
    f32x4 acc[4][8] = {};
    for (int k0 = 0; k0 < 256; k0 += 32) {
        if (k0) __syncthreads();
        stage_rows<128>(Ahi, Alo, bm0, 128, 256, k0, Ah, Al, tid);
        stage_rows<256>(Bhi, Blo, bn0, rB, 256, k0, Bh, Bl, tid);
        __syncthreads();
        mfma_tile256(Ah, Al, Bh, Bl, wm, wn, lane, acc);
    }
    int lr = lane & 15, lq = lane >> 4;
#pragma unroll
    for (int fm = 0; fm < 4; fm++) {
#pragma unroll
        for (int r = 0; r < 4; r++) {
            long row = bm0 + wm + fm * 16 + lq * 4 + r;  // < 512 always
#pragma unroll
            for (int fn = 0; fn < 8; fn++) {
                long col = bn0 + wn + fn * 16 + lr;
                if (col < N_ENTS) {
                    float v = acc[fm][fn][r];
                    out[row * N_ENTS + col] = 1.f / (1.f + __expf(-v));
                }
            }
        }
    }
}

// Lin GEMM: C[50000,256] = Xcat[50000,512] @ H512. A-side converts fp32
// interleave (Xef/Xrf) to split bf16 in-staging; Bt = HT512 split (256x512).
// Epilogue writes C fp32 AND its bf16 split (feeds next-layer XR operand).
__device__ __forceinline__ float4 lin_a_load(const float* __restrict__ Xef,
                                             const float* __restrict__ Xrf,
                                             int gm, int kk, int M) {
    int chunk = kk >> 6, s = kk & 63;
    const float* src = (chunk & 1) ? Xrf : Xef;
    float4 v = make_float4(0.f, 0.f, 0.f, 0.f);
    if (gm < M) v = *(const float4*)&src[(long)gm * 256 + (chunk >> 1) * 64 + s];
    return v;
}

__global__ __launch_bounds__(256, 2) void mfma_lin_kernel(
    const float* __restrict__ Xef, const float* __restrict__ Xrf,
    const u16* __restrict__ Bhi, const u16* __restrict__ Blo,
    float* __restrict__ C, u16* __restrict__ Chi, u16* __restrict__ Clo,
    int M) {
    __shared__ u16 Ah[128 * LSTR], Al[128 * LSTR];
    __shared__ u16 Bh[256 * LSTR], Bl[256 * LSTR];
    int tid = threadIdx.x, lane = tid & 63, wid = tid >> 6;
    int wm = (wid >> 1) * 64, wn = (wid & 1) * 128;
    int bm0 = blockIdx.y * 128;   // gridDim.x == 1 (N=256)
    f32x4 acc[4][8] = {};
    for (int k0 = 0; k0 < 512; k0 += 32) {
        if (k0) __syncthreads();
        // A: fp32 interleave -> split bf16 -> LDS (128 rows x 32 cols).
#pragma unroll
        for (int p = 0; p < 4; p++) {
            int idx = tid + p * 256;
            int r = idx >> 3, c4 = idx & 7;
            float4 v = lin_a_load(Xef, Xrf, bm0 + r, k0 + c4 * 4, M);
            u16 h0 = f2b(v.x), h1 = f2b(v.y), h2 = f2b(v.z), h3 = f2b(v.w);
            u16 l0 = f2b(v.x - b2f(h0)), l1 = f2b(v.y - b2f(h1));
            u16 l2 = f2b(v.z - b2f(h2)), l3 = f2b(v.w - b2f(h3));
            uint2 hp, lp;
            hp.x = (u32)h0 | ((u32)h1 << 16); hp.y = (u32)h2 | ((u32)h3 << 16);
            lp.x = (u32)l0 | ((u32)l1 << 16); lp.y = (u32)l2 | ((u32)l3 << 16);
            *(uint2*)&Ah[r * LSTR + c4 * 4] = hp;
            *(uint2*)&Al[r * LSTR + c4 * 4] = lp;
        }
        stage_rows<256>(Bhi, Blo, 0, 256, 512, k0, Bh, Bl, tid);
        __syncthreads();
        mfma_tile256(Ah, Al, Bh, Bl, wm, wn, lane, acc);
    }
    int lr = lane & 15, lq = lane >> 4;
#pragma unroll
    for (int fm = 0; fm < 4; fm++) {
#pragma unroll
        for (int r = 0; r < 4; r++) {
            long row = (long)bm0 + wm + fm * 16 + lq * 4 + r;
            if (row < M) {
#pragma unroll
                for (int fn = 0; fn < 8; fn++) {
                    long col = wn + fn * 16 + lr;
                    float v = acc[fm][fn][r];
                    C[row * 256 + col] = v;
                    u16 h = f2b(v);
                    Chi[row * 256 + col] = h;
                    Clo[row * 256 + col] = f2b(v - b2f(h));
                }
            }
        }
    }
}

// ---------------------------------------------------------------------------
// CSR build: histogram, single-block exclusive scan, ticket scatter.
// Edge payload packed as int2 {col, val-bits}: one 8B load per edge in agg.
// ---------------------------------------------------------------------------
__global__ __launch_bounds__(256) void hist_kernel(
    const int* __restrict__ rows, int* __restrict__ cnt, int n_edges) {
    int e = blockIdx.x * 256 + threadIdx.x;
    if (e < n_edges) atomicAdd(&cnt[rows[e]], 1);
}

__global__ __launch_bounds__(1024) void exscan_kernel(
    const int* __restrict__ cnt, int n, int* __restrict__ off) {
    __shared__ int part[1024];
    int t = threadIdx.x;
    int chunk = (n + 1023) / 1024;
    int lo = t * chunk;
    int hi = lo + chunk; if (hi > n) hi = n;
    int s = 0;
    for (int i = lo; i < hi; i++) s += cnt[i];
    part[t] = s;
    __syncthreads();
    for (int d = 1; d < 1024; d <<= 1) {
        int v = (t >= d) ? part[t - d] : 0;
        __syncthreads();
        part[t] += v;
        __syncthreads();
    }
    int base = (t == 0) ? 0 : part[t - 1];
    for (int i = lo; i < hi; i++) {
        off[i] = base;
        base += cnt[i];
    }
    if (hi >= n) off[n] = base;
}

__global__ __launch_bounds__(256) void scatter_kernel(
    const int* __restrict__ rows, const int* __restrict__ cols,
    const float* __restrict__ vals, int* __restrict__ cursor,
    int2* __restrict__ pack, int n_edges) {
    int e = blockIdx.x * 256 + threadIdx.x;
    if (e >= n_edges) return;
    int r = rows[e];
    int p = atomicAdd(&cursor[r], 1);
    pack[p] = make_int2(cols[e], __float_as_int(vals[e]));
}

// ---------------------------------------------------------------------------
// CSR aggregation: one 64-lane wave per row, lane owns 4 consecutive floats.
// ---------------------------------------------------------------------------
__global__ __launch_bounds__(256) void csr_agg_kernel(
    const float* __restrict__ support, const int* __restrict__ off,
    const int2* __restrict__ pack, float* __restrict__ agg, int n_rows) {
    int gid = blockIdx.x * 256 + threadIdx.x;
    int row = gid >> 6;
    int lane = gid & 63;
    if (row >= n_rows) return;
    int beg = off[row], end = off[row + 1];
    float4 acc = {0.f, 0.f, 0.f, 0.f};
    for (int e = beg; e < end; e++) {
        int2 cv = pack[e];
        float v = __int_as_float(cv.y);
        const float4 s = *(const float4*)(support + (long)cv.x * 256 + lane * 4);
        acc.x = fmaf(v, s.x, acc.x);
        acc.y = fmaf(v, s.y, acc.y);
        acc.z = fmaf(v, s.z, acc.z);
        acc.w = fmaf(v, s.w, acc.w);
    }
    *(float4*)(agg + (long)row * 256 + lane * 4) = acc;
}

// ---------------------------------------------------------------------------
// Column stats + BN apply (+tanh fp32 variant; split-output variant for hrn)
// ---------------------------------------------------------------------------
__global__ __launch_bounds__(256) void bn_stats_kernel(
    const float* __restrict__ x, int n, float* __restrict__ stats) {
    int col = threadIdx.x;
    int r0 = blockIdx.x * 256;
    int r1 = r0 + 256;
    if (r1 > n) r1 = n;
    float s = 0.f, sq = 0.f;
    for (int r = r0; r < r1; r++) {
        float v = x[(long)r * 256 + col];
        s += v;
        sq += v * v;
    }
    atomicAdd(&stats[col], s);
    atomicAdd(&stats[256 + col], sq);
}

template <bool TANH>
__global__ __launch_bounds__(256) void bn_apply_kernel(
    const float* __restrict__ x, float* __restrict__ y, int n,
    const float* __restrict__ gamma, const float* __restrict__ beta,
    const float* __restrict__ stats) {
    long total = (long)n * 256;
    float inv_n = 1.f / (float)n;
    for (long idx = (long)blockIdx.x * 256 + threadIdx.x; idx < total;
         idx += (long)gridDim.x * 256) {
        int col = (int)(idx & 255);
        float mean = stats[col] * inv_n;
        float var = stats[256 + col] * inv_n - mean * mean;
        float sc = rsqrtf(var + BN_EPS) * gamma[col];
        float v = (x[idx] - mean) * sc + beta[col];
        if (TANH) v = tanhf(v);
        y[idx] = v;
    }
}

// BN apply writing bf16 hi/lo split directly (no fp32 output; no tanh).
__global__ __launch_bounds__(256) void bn_apply_split_kernel(
    const float* __restrict__ x, u16* __restrict__ hi, u16* __restrict__ lo,
    int n, const float* __restrict__ gamma, const float* __restrict__ beta,
    const float* __restrict__ stats) {
    long total = (long)n * 256;
    float inv_n = 1.f / (float)n;
    long idx = (long)blockIdx.x * 256 + threadIdx.x;
    if (idx >= total) return;
    int col = (int)(idx & 255);
    float mean = stats[col] * inv_n;
    float var = stats[256 + col] * inv_n - mean * mean;
    float sc = rsqrtf(var + BN_EPS) * gamma[col];
    float v = (x[idx] - mean) * sc + beta[col];
    u16 h = f2b(v);
    hi[idx] = h;
    lo[idx] = f2b(v - b2f(h));
}

// ---------------------------------------------------------------------------
// Quaternion vec-vec multiplication
// ---------------------------------------------------------------------------
__global__ __launch_bounds__(256) void hr_kernel(
    const float* __restrict__ X, const float* __restrict__ R,
    const int* __restrict__ e1_idx, const int* __restrict__ r_idx,
    float* __restrict__ hr) {
    int idx = blockIdx.x * 256 + threadIdx.x;
    if (idx >= BATCH * 64) return;
    int b = idx >> 6, s = idx & 63;
    const float* h = X + (long)e1_idx[b] * 256;
    const float* p = R + (long)r_idx[b] * 256;
    float qr = h[s], qi = h[64 + s], qj = h[128 + s], qk = h[192 + s];
    float pr = p[s], pi = p[64 + s], pj = p[128 + s], pk = p[192 + s];
    float inv = rsqrtf(pr * pr + pi * pi + pj * pj + pk * pk);
    pr *= inv; pi *= inv; pj *= inv; pk *= inv;
    float* o = hr + (long)b * 256 + s;
    o[0]   = qr * pr - qi * pi - qj * pj - qk * pk;
    o[64]  = qi * pr + qr * pi - qk * pj + qj * pk;
    o[128] = qj * pr + qk * pi + qr * pj - qi * pk;
    o[192] = qk * pr - qj * pi + qi * pj + qr * pk;
}

// ---------------------------------------------------------------------------
// Host-side orchestration
// ---------------------------------------------------------------------------
struct Csr {
    int* off;
    int* cur;
    int2* pack;
};

struct Ws {
    float* supportBuf;  // (50500,256)
    float* aggA;        // (50500,256)
    float* aggB;        // (50000,256)
    float* XRcur;       // (50500,256)
    float* hr;          // (512,256)
    float* stats;       // 512
    u16* xr_hi;         // (50500,256) bf16 split of current XR
    u16* xr_lo;
    u16* hrn_hi;        // (512,256)
    u16* hrn_lo;
    u16* ht_hi;         // (256,512) max
    u16* ht_lo;
    Csr adj;
    Csr adjr;
};

static void build_csr(const int* rows, const int* cols, const float* vals,
                      int n_rows, const Csr& c, hipStream_t stream) {
    hipMemsetAsync(c.cur, 0, (size_t)n_rows * sizeof(int), stream);
    hist_kernel<<<(NEDGE + 255) / 256, 256, 0, stream>>>(rows, c.cur, NEDGE);
    exscan_kernel<<<1, 1024, 0, stream>>>(c.cur, n_rows, c.off);
    hipMemcpyAsync(c.cur, c.off, (size_t)n_rows * sizeof(int),
                   hipMemcpyDeviceToDevice, stream);
    scatter_kernel<<<(NEDGE + 255) / 256, 256, 0, stream>>>(
        rows, cols, vals, c.cur, c.pack, NEDGE);
}

static void run_bn(float* buf, float* outbuf, int n, const float* gamma,
                   const float* beta, bool do_tanh, const Ws& w,
                   hipStream_t stream) {
    hipMemsetAsync(w.stats, 0, 512 * sizeof(float), stream);
    bn_stats_kernel<<<(n + 255) / 256, 256, 0, stream>>>(buf, n, w.stats);
    long total = (long)n * 256;
    int blocks = (int)((total + 255) / 256);
    if (blocks > 2048) blocks = 2048;
    if (do_tanh)
        bn_apply_kernel<true><<<blocks, 256, 0, stream>>>(buf, outbuf, n, gamma, beta, w.stats);
    else
        bn_apply_kernel<false><<<blocks, 256, 0, stream>>>(buf, outbuf, n, gamma, beta, w.stats);
}

static void run_split(const float* x, u16* hi, u16* lo, long n,
                      hipStream_t stream) {
    long n4 = n / 4;
    split_kernel<<<(int)((n4 + 255) / 256), 256, 0, stream>>>(x, hi, lo, n4);
}

static void run_q4gnn(int n, const Csr& c, const float* W, const float* gamma,
                      const float* beta, float* agg, const Ws& w,
                      hipStream_t stream) {
    build_ht_kernel<<<(256 * 256) / 256, 256, 0, stream>>>(W, w.ht_hi, w.ht_lo, 64);
    dim3 g(1, (n + 127) / 128);
    mfma_gemm_bt_kernel<<<g, 256, 0, stream>>>(
        w.xr_hi, w.xr_lo, w.ht_hi, w.ht_lo, w.supportBuf, n, 256, 256);
    int agg_blocks = (n * 64 + 255) / 256;
    csr_agg_kernel<<<agg_blocks, 256, 0, stream>>>(
        w.supportBuf, c.off, c.pack, agg, n);
    run_bn(agg, agg, n, gamma, beta, true, w, stream);
}

static void run_score(const float* X, const float* R, const int* e1_idx,
                      const int* r_idx, const float* gamma, const float* beta,
                      float* out_l, const Ws& w, hipStream_t stream) {
    hr_kernel<<<(BATCH * 64) / 256, 256, 0, stream>>>(X, R, e1_idx, r_idx, w.hr);
    hipMemsetAsync(w.stats, 0, 512 * sizeof(float), stream);
    bn_stats_kernel<<<(BATCH + 255) / 256, 256, 0, stream>>>(w.hr, BATCH, w.stats);
    bn_apply_split_kernel<<<(BATCH * 256) / 256, 256, 0, stream>>>(
        w.hr, w.hrn_hi, w.hrn_lo, BATCH, gamma, beta, w.stats);
    dim3 g((N_ENTS + 255) / 256, BATCH / 128);
    mfma_score_kernel<<<g, 256, 0, stream>>>(
        w.hrn_hi, w.hrn_lo, w.xr_hi, w.xr_lo, out_l);
}

extern "C" void kernel_launch(void* const* d_in, const int* in_sizes, int n_in,
                              void* d_out, int out_size, void* d_ws, size_t ws_size,
                              hipStream_t stream) {
    const int*   e1_idx     = (const int*)d_in[0];
    const int*   r_idx      = (const int*)d_in[1];
    const float* emb        = (const float*)d_in[2];
    const float* gcn1_w     = (const float*)d_in[3];
    const float* gcn2_w     = (const float*)d_in[4];
    const float* gcn1_gamma = (const float*)d_in[5];
    const float* gcn1_beta  = (const float*)d_in[6];
    const float* gcn2_gamma = (const float*)d_in[7];
    const float* gcn2_beta  = (const float*)d_in[8];
    const float* lin_ents   = (const float*)d_in[9];
    const float* bn_s_gamma = (const float*)d_in[10];
    const float* bn_s_beta  = (const float*)d_in[11];
    const int*   adj_rows   = (const int*)d_in[12];
    const int*   adj_cols   = (const int*)d_in[13];
    const float* adj_vals   = (const float*)d_in[14];
    const int*   adjr_rows  = (const int*)d_in[15];
    const int*   adjr_cols  = (const int*)d_in[16];
    const float* adjr_vals  = (const float*)d_in[17];
    float* out = (float*)d_out;

    Ws w;
    float* f = (float*)d_ws;
    w.supportBuf = f; f += (long)N_ALL * EMB;
    w.aggA       = f; f += (long)N_ALL * EMB;
    w.aggB       = f; f += (long)N_ENTS * EMB;
    w.XRcur      = f; f += (long)N_ALL * EMB;
    w.hr         = f; f += BATCH * EMB;
    w.stats      = f; f += 512;
    w.xr_hi  = (u16*)f; f += (long)N_ALL * EMB / 2;
    w.xr_lo  = (u16*)f; f += (long)N_ALL * EMB / 2;
    w.hrn_hi = (u16*)f; f += BATCH * EMB / 2;
    w.hrn_lo = (u16*)f; f += BATCH * EMB / 2;
    w.ht_hi  = (u16*)f; f += 256 * 512 / 2;
    w.ht_lo  = (u16*)f; f += 256 * 512 / 2;
    int* ip = (int*)f;
    w.adj.pack  = (int2*)ip; ip += 2 * NEDGE;
    w.adjr.pack = (int2*)ip; ip += 2 * NEDGE;
    w.adj.off    = ip; ip += N_ENTS + 1;
    w.adj.cur    = ip; ip += N_ENTS;
    w.adjr.off   = ip; ip += N_ALL + 1;
    w.adjr.cur   = ip; ip += N_ALL;

    // Build both CSRs once; reused by both layers.
    build_csr(adj_rows, adj_cols, adj_vals, N_ENTS, w.adj, stream);
    build_csr(adjr_rows, adjr_cols, adjr_vals, N_ALL, w.adjr, stream);

    // Split embeddings (entities+rels) once.
    run_split(emb, w.xr_hi, w.xr_lo, (long)N_ALL * EMB, stream);

    // score 0
    run_score(emb, emb + (long)N_ENTS * EMB, e1_idx, r_idx,
              bn_s_gamma, bn_s_beta, out, w, stream);

    for (int l = 0; l < 2; l++) {
        run_q4gnn(N_ALL, w.adjr, gcn2_w + (long)l * 64 * 256,
                  gcn2_gamma + l * 256, gcn2_beta + l * 256, w.aggA, w, stream);
        run_q4gnn(N_ENTS, w.adj, gcn1_w + (long)l * 64 * 256,
                  gcn1_gamma + l * 256, gcn1_beta + l * 256, w.aggB, w, stream);
        build_ht_kernel<<<(256 * 512) / 256, 256, 0, stream>>>(
            lin_ents + (long)l * 128 * 256, w.ht_hi, w.ht_lo, 128);
        dim3 g(1, (N_ENTS + 127) / 128);
        mfma_lin_kernel<<<g, 256, 0, stream>>>(
            w.aggB, w.aggA, w.ht_hi, w.ht_lo, w.XRcur, w.xr_hi, w.xr_lo, N_ENTS);
        // Rels rows: fp32 copy + small split into the xr bf16 buffers.
        hipMemcpyAsync(w.XRcur + (long)N_ENTS * EMB, w.aggA + (long)N_ENTS * EMB,
                       (size_t)N_RELS * EMB * sizeof(float),
                       hipMemcpyDeviceToDevice, stream);
        run_split(w.XRcur + (long)N_ENTS * EMB, w.xr_hi + (long)N_ENTS * EMB,
                  w.xr_lo + (long)N_ENTS * EMB, (long)N_RELS * EMB, stream);
        run_score(w.XRcur, w.XRcur + (long)N_ENTS * EMB, e1_idx, r_idx,
                  bn_s_gamma + (l + 1) * 256, bn_s_beta + (l + 1) * 256,
                  out + (long)(l + 1) * BATCH * N_ENTS, w, stream);
    }
}

// Round 8
// 1884.369 us; speedup vs baseline: 1.6619x; 1.0051x over previous
//
#include <hip/hip_runtime.h>
#include <math.h>

#define N_ENTS 50000
#define N_RELS 500
#define N_ALL  50500
#define EMB    256
#define NEDGE  400000
#define BATCH  512
#define BN_EPS 1e-5f

typedef unsigned short u16;
typedef unsigned int   u32;
typedef __attribute__((ext_vector_type(8))) short s16x8;  // 8 bf16 (4 VGPRs)
typedef __attribute__((ext_vector_type(4))) float f32x4;  // MFMA acc

// LDS row stride in u16 for 32-wide K tiles: 40 shorts = 80 B, 16B-aligned
// chunks, 20-bank-quad stride => <=2-way (free) conflicts on fragment reads.
#define LSTR 40

// ---------------------------------------------------------------------------
// bf16 split helpers (RNE). x = hi + lo with |x-hi-lo| ~ 2^-17|x|.
// ---------------------------------------------------------------------------
__device__ __forceinline__ u16 f2b(float x) {
    u32 u = __float_as_uint(x);
    return (u16)((u + 0x7fffu + ((u >> 16) & 1u)) >> 16);
}
__device__ __forceinline__ float b2f(u16 h) {
    return __uint_as_float((u32)h << 16);
}

// Split fp32 array into bf16 hi/lo arrays. n4 = count of float4 groups.
__global__ __launch_bounds__(256) void split_kernel(
    const float* __restrict__ x, u16* __restrict__ hi, u16* __restrict__ lo,
    long n4) {
    long i = (long)blockIdx.x * 256 + threadIdx.x;
    if (i >= n4) return;
    float4 v = ((const float4*)x)[i];
    u16 h0 = f2b(v.x), h1 = f2b(v.y), h2 = f2b(v.z), h3 = f2b(v.w);
    u16 l0 = f2b(v.x - b2f(h0)), l1 = f2b(v.y - b2f(h1));
    u16 l2 = f2b(v.z - b2f(h2)), l3 = f2b(v.w - b2f(h3));
    uint2 hp, lp;
    hp.x = (u32)h0 | ((u32)h1 << 16); hp.y = (u32)h2 | ((u32)h3 << 16);
    lp.x = (u32)l0 | ((u32)l1 << 16); lp.y = (u32)l2 | ((u32)l3 << 16);
    ((uint2*)hi)[i] = hp;
    ((uint2*)lo)[i] = lp;
}

// ---------------------------------------------------------------------------
// Build TRANSPOSED hamilton HT[n][k] (256 rows, K=4P cols), pre-split bf16.
// ---------------------------------------------------------------------------
__global__ __launch_bounds__(256) void build_ht_kernel(
    const float* __restrict__ W, u16* __restrict__ Hhi, u16* __restrict__ Hlo,
    int P) {
    int K4 = 4 * P;
    int idx = blockIdx.x * 256 + threadIdx.x;
    int total = 256 * K4;
    if (idx >= total) return;
    int n = idx / K4, k = idx - n * K4;
    int a = k / P, p = k - a * P;
    int c = n >> 6, s = n & 63;
    const int  comp[4][4] = {{0,1,2,3},{1,0,3,2},{2,3,0,1},{3,2,1,0}};
    const float sgn[4][4] = {{1.f,1.f,1.f,1.f},
                             {-1.f,1.f,1.f,-1.f},
                             {-1.f,-1.f,1.f,1.f},
                             {-1.f,1.f,-1.f,1.f}};
    float v = sgn[a][c] * W[p * 256 + comp[a][c] * 64 + s];
    u16 h = f2b(v);
    Hhi[idx] = h;
    Hlo[idx] = f2b(v - b2f(h));
}

// ---------------------------------------------------------------------------
// MFMA GEMM core (BT form): C[m][n] = sum_k A[m][k]*Bt[n][k].
// Block 256 thr = 4 waves as 2Mx2N, tile 128x256, wave tile 64x128.
// K-step 32, mfma_f32_16x16x32_bf16, split-bf16 3-term.
// ---------------------------------------------------------------------------
template <int ROWS>
__device__ __forceinline__ void stage_rows(
    const u16* __restrict__ Shi, const u16* __restrict__ Slo,
    long row0, int rows_left, int K, int k0,
    u16* __restrict__ Lh, u16* __restrict__ Ll, int tid) {
#pragma unroll
    for (int p = 0; p < ROWS / 64; p++) {
        int idx = tid + p * 256;
        int r = idx >> 2, c = idx & 3;
        uint4 vh = make_uint4(0, 0, 0, 0), vl = make_uint4(0, 0, 0, 0);
        if (r < rows_left) {
            long base = (row0 + r) * (long)K + k0 + c * 8;
            vh = *(const uint4*)&Shi[base];
            vl = *(const uint4*)&Slo[base];
        }
        *(uint4*)&Lh[r * LSTR + c * 8] = vh;
        *(uint4*)&Ll[r * LSTR + c * 8] = vl;
    }
}

__device__ __forceinline__ void mfma_tile256(
    const u16* __restrict__ Ah, const u16* __restrict__ Al,
    const u16* __restrict__ Bh, const u16* __restrict__ Bl,
    int wm, int wn, int lane, f32x4 acc[4][8]) {
    int lr = lane & 15, kg = lane >> 4;
    s16x8 ah[4], al[4];
#pragma unroll
    for (int fm = 0; fm < 4; fm++) {
        int off = (wm + fm * 16 + lr) * LSTR + kg * 8;
        ah[fm] = *(const s16x8*)&Ah[off];
        al[fm] = *(const s16x8*)&Al[off];
    }
#pragma unroll
    for (int fn = 0; fn < 8; fn++) {
        int off = (wn + fn * 16 + lr) * LSTR + kg * 8;
        s16x8 bh = *(const s16x8*)&Bh[off];
        s16x8 bl = *(const s16x8*)&Bl[off];
#pragma unroll
        for (int fm = 0; fm < 4; fm++) {
            acc[fm][fn] = __builtin_amdgcn_mfma_f32_16x16x32_bf16(
                ah[fm], bh, acc[fm][fn], 0, 0, 0);
            acc[fm][fn] = __builtin_amdgcn_mfma_f32_16x16x32_bf16(
                ah[fm], bl, acc[fm][fn], 0, 0, 0);
            acc[fm][fn] = __builtin_amdgcn_mfma_f32_16x16x32_bf16(
                al[fm], bh, acc[fm][fn], 0, 0, 0);
        }
    }
}

// Support GEMM: A=XR split, Bt=HT split, N=256 (gridDim.x=1). fp32 output
// (bf16 output measured FAILING: absmax 0.17 vs 0.02 threshold, round 7).
__global__ __launch_bounds__(256, 2) void mfma_support_kernel(
    const u16* __restrict__ Ahi, const u16* __restrict__ Alo,
    const u16* __restrict__ Bhi, const u16* __restrict__ Blo,
    float* __restrict__ C, int M, int N, int K) {
    __shared__ u16 Ah[128 * LSTR], Al[128 * LSTR];
    __shared__ u16 Bh[256 * LSTR], Bl[256 * LSTR];
    int tid = threadIdx.x, lane = tid & 63, wid = tid >> 6;
    int wm = (wid >> 1) * 64, wn = (wid & 1) * 128;
    long bm0 = (long)blockIdx.y * 128, bn0 = (long)blockIdx.x * 256;
    int rA = (int)(((long)M - bm0 < 128) ? (long)M - bm0 : 128);
    int rB = (int)(((long)N - bn0 < 256) ? (long)N - bn0 : 256);
    f32x4 acc[4][8] = {};
    for (int k0 = 0; k0 < K; k0 += 32) {
        if (k0) __syncthreads();
        stage_rows<128>(Ahi, Alo, bm0, rA, K, k0, Ah, Al, tid);
        stage_rows<256>(Bhi, Blo, bn0, rB, K, k0, Bh, Bl, tid);
        __syncthreads();
        mfma_tile256(Ah, Al, Bh, Bl, wm, wn, lane, acc);
    }
    int lr = lane & 15, lq = lane >> 4;
#pragma unroll
    for (int fm = 0; fm < 4; fm++) {
#pragma unroll
        for (int r = 0; r < 4; r++) {
            long row = bm0 + wm + fm * 16 + lq * 4 + r;
            if (row < M) {
#pragma unroll
                for (int fn = 0; fn < 8; fn++) {
                    long col = bn0 + wn + fn * 16 + lr;
                    if (col < N) C[row * N + col] = acc[fm][fn][r];
                }
            }
        }
    }
}

// Score GEMM: A=hrn split (512x256), Bt=X split (50000x256), sigmoid out.
__global__ __launch_bounds__(256, 2) void mfma_score_kernel(
    const u16* __restrict__ Ahi, const u16* __restrict__ Alo,
    const u16* __restrict__ Bhi, const u16* __restrict__ Blo,
    float* __restrict__ out) {
    __shared__ u16 Ah[128 * LSTR], Al[128 * LSTR];
    __shared__ u16 Bh[256 * LSTR], Bl[256 * LSTR];
    int tid = threadIdx.x, lane = tid & 63, wid = tid >> 6;
    int wm = (wid >> 1) * 64, wn = (wid & 1) * 128;
    long bm0 = (long)blockIdx.y * 128, bn0 = (long)blockIdx.x * 256;
    int rB = (int)(((long)N_ENTS - bn0 < 256) ? (long)N_ENTS - bn0 : 256);
    f32x4 acc[4][8] = {};
    for (int k0 = 0; k0 < 256; k0 += 32) {
        if (k0) __syncthreads();
        stage_rows<128>(Ahi, Alo, bm0, 128, 256, k0, Ah, Al, tid);
        stage_rows<256>(Bhi, Blo, bn0, rB, 256, k0, Bh, Bl, tid);
        __syncthreads();
        mfma_tile256(Ah, Al, Bh, Bl, wm, wn, lane, acc);
    }
    int lr = lane & 15, lq = lane >> 4;
#pragma unroll
    for (int fm = 0; fm < 4; fm++) {
#pragma unroll
        for (int r = 0; r < 4; r++) {
            long row = bm0 + wm + fm * 16 + lq * 4 + r;  // < 512 always
#pragma unroll
            for (int fn = 0; fn < 8; fn++) {
                long col = bn0 + wn + fn * 16 + lr;
                if (col < N_ENTS) {
                    float v = acc[fm][fn][r];
                    out[row * N_ENTS + col] = 1.f / (1.f + __expf(-v));
                }
            }
        }
    }
}

// Lin GEMM: Xcat[50000,512] @ H512. A-side converts fp32 interleave
// (Xef/Xrf) to split bf16 in-staging; Bt = HT512 split (256x512).
// Epilogue writes ONLY the bf16 hi/lo split (reconstruction err 2^-17;
// all downstream consumers read the split).
__device__ __forceinline__ float4 lin_a_load(const float* __restrict__ Xef,
                                             const float* __restrict__ Xrf,
                                             int gm, int kk, int M) {
    int chunk = kk >> 6, s = kk & 63;
    const float* src = (chunk & 1) ? Xrf : Xef;
    float4 v = make_float4(0.f, 0.f, 0.f, 0.f);
    if (gm < M) v = *(const float4*)&src[(long)gm * 256 + (chunk >> 1) * 64 + s];
    return v;
}

__global__ __launch_bounds__(256, 2) void mfma_lin_kernel(
    const float* __restrict__ Xef, const float* __restrict__ Xrf,
    const u16* __restrict__ Bhi, const u16* __restrict__ Blo,
    u16* __restrict__ Chi, u16* __restrict__ Clo, int M) {
    __shared__ u16 Ah[128 * LSTR], Al[128 * LSTR];
    __shared__ u16 Bh[256 * LSTR], Bl[256 * LSTR];
    int tid = threadIdx.x, lane = tid & 63, wid = tid >> 6;
    int wm = (wid >> 1) * 64, wn = (wid & 1) * 128;
    int bm0 = blockIdx.y * 128;   // gridDim.x == 1 (N=256)
    f32x4 acc[4][8] = {};
    for (int k0 = 0; k0 < 512; k0 += 32) {
        if (k0) __syncthreads();
#pragma unroll
        for (int p = 0; p < 4; p++) {
            int idx = tid + p * 256;
            int r = idx >> 3, c4 = idx & 7;
            float4 v = lin_a_load(Xef, Xrf, bm0 + r, k0 + c4 * 4, M);
            u16 h0 = f2b(v.x), h1 = f2b(v.y), h2 = f2b(v.z), h3 = f2b(v.w);
            u16 l0 = f2b(v.x - b2f(h0)), l1 = f2b(v.y - b2f(h1));
            u16 l2 = f2b(v.z - b2f(h2)), l3 = f2b(v.w - b2f(h3));
            uint2 hp, lp;
            hp.x = (u32)h0 | ((u32)h1 << 16); hp.y = (u32)h2 | ((u32)h3 << 16);
            lp.x = (u32)l0 | ((u32)l1 << 16); lp.y = (u32)l2 | ((u32)l3 << 16);
            *(uint2*)&Ah[r * LSTR + c4 * 4] = hp;
            *(uint2*)&Al[r * LSTR + c4 * 4] = lp;
        }
        stage_rows<256>(Bhi, Blo, 0, 256, 512, k0, Bh, Bl, tid);
        __syncthreads();
        mfma_tile256(Ah, Al, Bh, Bl, wm, wn, lane, acc);
    }
    int lr = lane & 15, lq = lane >> 4;
#pragma unroll
    for (int fm = 0; fm < 4; fm++) {
#pragma unroll
        for (int r = 0; r < 4; r++) {
            long row = (long)bm0 + wm + fm * 16 + lq * 4 + r;
            if (row < M) {
#pragma unroll
                for (int fn = 0; fn < 8; fn++) {
                    long col = wn + fn * 16 + lr;
                    float v = acc[fm][fn][r];
                    u16 h = f2b(v);
                    Chi[row * 256 + col] = h;
                    Clo[row * 256 + col] = f2b(v - b2f(h));
                }
            }
        }
    }
}

// ---------------------------------------------------------------------------
// CSR build: histogram, single-block exclusive scan, ticket scatter.
// ---------------------------------------------------------------------------
__global__ __launch_bounds__(256) void hist_kernel(
    const int* __restrict__ rows, int* __restrict__ cnt, int n_edges) {
    int e = blockIdx.x * 256 + threadIdx.x;
    if (e < n_edges) atomicAdd(&cnt[rows[e]], 1);
}

__global__ __launch_bounds__(1024) void exscan_kernel(
    const int* __restrict__ cnt, int n, int* __restrict__ off) {
    __shared__ int part[1024];
    int t = threadIdx.x;
    int chunk = (n + 1023) / 1024;
    int lo = t * chunk;
    int hi = lo + chunk; if (hi > n) hi = n;
    int s = 0;
    for (int i = lo; i < hi; i++) s += cnt[i];
    part[t] = s;
    __syncthreads();
    for (int d = 1; d < 1024; d <<= 1) {
        int v = (t >= d) ? part[t - d] : 0;
        __syncthreads();
        part[t] += v;
        __syncthreads();
    }
    int base = (t == 0) ? 0 : part[t - 1];
    for (int i = lo; i < hi; i++) {
        off[i] = base;
        base += cnt[i];
    }
    if (hi >= n) off[n] = base;
}

__global__ __launch_bounds__(256) void scatter_kernel(
    const int* __restrict__ rows, const int* __restrict__ cols,
    const float* __restrict__ vals, int* __restrict__ cursor,
    int2* __restrict__ pack, int n_edges) {
    int e = blockIdx.x * 256 + threadIdx.x;
    if (e >= n_edges) return;
    int r = rows[e];
    int p = atomicAdd(&cursor[r], 1);
    pack[p] = make_int2(cols[e], __float_as_int(vals[e]));
}

// ---------------------------------------------------------------------------
// CSR aggregation: one 64-lane wave per row, lane owns 4 consecutive floats.
// ---------------------------------------------------------------------------
__global__ __launch_bounds__(256) void csr_agg_kernel(
    const float* __restrict__ support, const int* __restrict__ off,
    const int2* __restrict__ pack, float* __restrict__ agg, int n_rows) {
    int gid = blockIdx.x * 256 + threadIdx.x;
    int row = gid >> 6;
    int lane = gid & 63;
    if (row >= n_rows) return;
    int beg = off[row], end = off[row + 1];
    float4 acc = {0.f, 0.f, 0.f, 0.f};
    for (int e = beg; e < end; e++) {
        int2 cv = pack[e];
        float v = __int_as_float(cv.y);
        const float4 s = *(const float4*)(support + (long)cv.x * 256 + lane * 4);
        acc.x = fmaf(v, s.x, acc.x);
        acc.y = fmaf(v, s.y, acc.y);
        acc.z = fmaf(v, s.z, acc.z);
        acc.w = fmaf(v, s.w, acc.w);
    }
    *(float4*)(agg + (long)row * 256 + lane * 4) = acc;
}

// ---------------------------------------------------------------------------
// Column stats + BN apply (+tanh fp32 variant; split-output variant for hrn)
// ---------------------------------------------------------------------------
__global__ __launch_bounds__(256) void bn_stats_kernel(
    const float* __restrict__ x, int n, float* __restrict__ stats) {
    int col = threadIdx.x;
    int r0 = blockIdx.x * 256;
    int r1 = r0 + 256;
    if (r1 > n) r1 = n;
    float s = 0.f, sq = 0.f;
    for (int r = r0; r < r1; r++) {
        float v = x[(long)r * 256 + col];
        s += v;
        sq += v * v;
    }
    atomicAdd(&stats[col], s);
    atomicAdd(&stats[256 + col], sq);
}

template <bool TANH>
__global__ __launch_bounds__(256) void bn_apply_kernel(
    const float* __restrict__ x, float* __restrict__ y, int n,
    const float* __restrict__ gamma, const float* __restrict__ beta,
    const float* __restrict__ stats) {
    long total = (long)n * 256;
    float inv_n = 1.f / (float)n;
    for (long idx = (long)blockIdx.x * 256 + threadIdx.x; idx < total;
         idx += (long)gridDim.x * 256) {
        int col = (int)(idx & 255);
        float mean = stats[col] * inv_n;
        float var = stats[256 + col] * inv_n - mean * mean;
        float sc = rsqrtf(var + BN_EPS) * gamma[col];
        float v = (x[idx] - mean) * sc + beta[col];
        if (TANH) v = tanhf(v);
        y[idx] = v;
    }
}

// BN apply writing bf16 hi/lo split directly (no fp32 output; no tanh).
__global__ __launch_bounds__(256) void bn_apply_split_kernel(
    const float* __restrict__ x, u16* __restrict__ hi, u16* __restrict__ lo,
    int n, const float* __restrict__ gamma, const float* __restrict__ beta,
    const float* __restrict__ stats) {
    long total = (long)n * 256;
    float inv_n = 1.f / (float)n;
    long idx = (long)blockIdx.x * 256 + threadIdx.x;
    if (idx >= total) return;
    int col = (int)(idx & 255);
    float mean = stats[col] * inv_n;
    float var = stats[256 + col] * inv_n - mean * mean;
    float sc = rsqrtf(var + BN_EPS) * gamma[col];
    float v = (x[idx] - mean) * sc + beta[col];
    u16 h = f2b(v);
    hi[idx] = h;
    lo[idx] = f2b(v - b2f(h));
}

// ---------------------------------------------------------------------------
// Quaternion vec-vec multiplication. X/R rows reconstructed from the shared
// xr bf16 hi/lo split (reconstruction error ~2^-17 — below GEMM path error).
// ---------------------------------------------------------------------------
__global__ __launch_bounds__(256) void hr_kernel(
    const u16* __restrict__ xhi, const u16* __restrict__ xlo,
    const int* __restrict__ e1_idx, const int* __restrict__ r_idx,
    float* __restrict__ hr) {
    int idx = blockIdx.x * 256 + threadIdx.x;
    if (idx >= BATCH * 64) return;
    int b = idx >> 6, s = idx & 63;
    long hrow = (long)e1_idx[b] * 256;
    long prow = ((long)N_ENTS + r_idx[b]) * 256;
    float qr = b2f(xhi[hrow + s])       + b2f(xlo[hrow + s]);
    float qi = b2f(xhi[hrow + 64 + s])  + b2f(xlo[hrow + 64 + s]);
    float qj = b2f(xhi[hrow + 128 + s]) + b2f(xlo[hrow + 128 + s]);
    float qk = b2f(xhi[hrow + 192 + s]) + b2f(xlo[hrow + 192 + s]);
    float pr = b2f(xhi[prow + s])       + b2f(xlo[prow + s]);
    float pi = b2f(xhi[prow + 64 + s])  + b2f(xlo[prow + 64 + s]);
    float pj = b2f(xhi[prow + 128 + s]) + b2f(xlo[prow + 128 + s]);
    float pk = b2f(xhi[prow + 192 + s]) + b2f(xlo[prow + 192 + s]);
    float inv = rsqrtf(pr * pr + pi * pi + pj * pj + pk * pk);
    pr *= inv; pi *= inv; pj *= inv; pk *= inv;
    float* o = hr + (long)b * 256 + s;
    o[0]   = qr * pr - qi * pi - qj * pj - qk * pk;
    o[64]  = qi * pr + qr * pi - qk * pj + qj * pk;
    o[128] = qj * pr + qk * pi + qr * pj - qi * pk;
    o[192] = qk * pr - qj * pi + qi * pj + qr * pk;
}

// ---------------------------------------------------------------------------
// Host-side orchestration
// ---------------------------------------------------------------------------
struct Csr {
    int* off;
    int* cur;
    int2* pack;
};

struct Ws {
    float* supportBuf;  // (50500,256) fp32
    float* aggA;        // (50500,256)
    float* aggB;        // (50000,256)
    float* hr;          // (512,256)
    float* stats;       // 512
    u16* xr_hi;         // (50500,256) bf16 split of current XR
    u16* xr_lo;
    u16* hrn_hi;        // (512,256)
    u16* hrn_lo;
    u16* ht_hi;         // (256,512) max
    u16* ht_lo;
    Csr adj;
    Csr adjr;
};

static void build_csr(const int* rows, const int* cols, const float* vals,
                      int n_rows, const Csr& c, hipStream_t stream) {
    hipMemsetAsync(c.cur, 0, (size_t)n_rows * sizeof(int), stream);
    hist_kernel<<<(NEDGE + 255) / 256, 256, 0, stream>>>(rows, c.cur, NEDGE);
    exscan_kernel<<<1, 1024, 0, stream>>>(c.cur, n_rows, c.off);
    hipMemcpyAsync(c.cur, c.off, (size_t)n_rows * sizeof(int),
                   hipMemcpyDeviceToDevice, stream);
    scatter_kernel<<<(NEDGE + 255) / 256, 256, 0, stream>>>(
        rows, cols, vals, c.cur, c.pack, NEDGE);
}

static void run_bn(float* buf, float* outbuf, int n, const float* gamma,
                   const float* beta, bool do_tanh, const Ws& w,
                   hipStream_t stream) {
    hipMemsetAsync(w.stats, 0, 512 * sizeof(float), stream);
    bn_stats_kernel<<<(n + 255) / 256, 256, 0, stream>>>(buf, n, w.stats);
    long total = (long)n * 256;
    int blocks = (int)((total + 255) / 256);
    if (blocks > 2048) blocks = 2048;
    if (do_tanh)
        bn_apply_kernel<true><<<blocks, 256, 0, stream>>>(buf, outbuf, n, gamma, beta, w.stats);
    else
        bn_apply_kernel<false><<<blocks, 256, 0, stream>>>(buf, outbuf, n, gamma, beta, w.stats);
}

static void run_split(const float* x, u16* hi, u16* lo, long n,
                      hipStream_t stream) {
    long n4 = n / 4;
    split_kernel<<<(int)((n4 + 255) / 256), 256, 0, stream>>>(x, hi, lo, n4);
}

static void run_q4gnn(int n, const Csr& c, const float* W, const float* gamma,
                      const float* beta, float* agg, const Ws& w,
                      hipStream_t stream) {
    build_ht_kernel<<<(256 * 256) / 256, 256, 0, stream>>>(W, w.ht_hi, w.ht_lo, 64);
    dim3 g(1, (n + 127) / 128);
    mfma_support_kernel<<<g, 256, 0, stream>>>(
        w.xr_hi, w.xr_lo, w.ht_hi, w.ht_lo, w.supportBuf, n, 256, 256);
    int agg_blocks = (n * 64 + 255) / 256;
    csr_agg_kernel<<<agg_blocks, 256, 0, stream>>>(
        w.supportBuf, c.off, c.pack, agg, n);
    run_bn(agg, agg, n, gamma, beta, true, w, stream);
}

static void run_score(const int* e1_idx, const int* r_idx, const float* gamma,
                      const float* beta, float* out_l, const Ws& w,
                      hipStream_t stream) {
    hr_kernel<<<(BATCH * 64) / 256, 256, 0, stream>>>(
        w.xr_hi, w.xr_lo, e1_idx, r_idx, w.hr);
    hipMemsetAsync(w.stats, 0, 512 * sizeof(float), stream);
    bn_stats_kernel<<<(BATCH + 255) / 256, 256, 0, stream>>>(w.hr, BATCH, w.stats);
    bn_apply_split_kernel<<<(BATCH * 256) / 256, 256, 0, stream>>>(
        w.hr, w.hrn_hi, w.hrn_lo, BATCH, gamma, beta, w.stats);
    dim3 g((N_ENTS + 255) / 256, BATCH / 128);
    mfma_score_kernel<<<g, 256, 0, stream>>>(
        w.hrn_hi, w.hrn_lo, w.xr_hi, w.xr_lo, out_l);
}

extern "C" void kernel_launch(void* const* d_in, const int* in_sizes, int n_in,
                              void* d_out, int out_size, void* d_ws, size_t ws_size,
                              hipStream_t stream) {
    const int*   e1_idx     = (const int*)d_in[0];
    const int*   r_idx      = (const int*)d_in[1];
    const float* emb        = (const float*)d_in[2];
    const float* gcn1_w     = (const float*)d_in[3];
    const float* gcn2_w     = (const float*)d_in[4];
    const float* gcn1_gamma = (const float*)d_in[5];
    const float* gcn1_beta  = (const float*)d_in[6];
    const float* gcn2_gamma = (const float*)d_in[7];
    const float* gcn2_beta  = (const float*)d_in[8];
    const float* lin_ents   = (const float*)d_in[9];
    const float* bn_s_gamma = (const float*)d_in[10];
    const float* bn_s_beta  = (const float*)d_in[11];
    const int*   adj_rows   = (const int*)d_in[12];
    const int*   adj_cols   = (const int*)d_in[13];
    const float* adj_vals   = (const float*)d_in[14];
    const int*   adjr_rows  = (const int*)d_in[15];
    const int*   adjr_cols  = (const int*)d_in[16];
    const float* adjr_vals  = (const float*)d_in[17];
    float* out = (float*)d_out;

    Ws w;
    float* f = (float*)d_ws;
    w.supportBuf = f; f += (long)N_ALL * EMB;
    w.aggA       = f; f += (long)N_ALL * EMB;
    w.aggB       = f; f += (long)N_ENTS * EMB;
    w.hr         = f; f += BATCH * EMB;
    w.stats      = f; f += 512;
    w.xr_hi  = (u16*)f; f += (long)N_ALL * EMB / 2;
    w.xr_lo  = (u16*)f; f += (long)N_ALL * EMB / 2;
    w.hrn_hi = (u16*)f; f += BATCH * EMB / 2;
    w.hrn_lo = (u16*)f; f += BATCH * EMB / 2;
    w.ht_hi  = (u16*)f; f += 256 * 512 / 2;
    w.ht_lo  = (u16*)f; f += 256 * 512 / 2;
    int* ip = (int*)f;
    w.adj.pack  = (int2*)ip; ip += 2 * NEDGE;
    w.adjr.pack = (int2*)ip; ip += 2 * NEDGE;
    w.adj.off    = ip; ip += N_ENTS + 1;
    w.adj.cur    = ip; ip += N_ENTS;
    w.adjr.off   = ip; ip += N_ALL + 1;
    w.adjr.cur   = ip; ip += N_ALL;

    // Build both CSRs once; reused by both layers.
    build_csr(adj_rows, adj_cols, adj_vals, N_ENTS, w.adj, stream);
    build_csr(adjr_rows, adjr_cols, adjr_vals, N_ALL, w.adjr, stream);

    // Split embeddings (entities+rels) once into the shared xr buffers.
    run_split(emb, w.xr_hi, w.xr_lo, (long)N_ALL * EMB, stream);

    // score 0
    run_score(e1_idx, r_idx, bn_s_gamma, bn_s_beta, out, w, stream);

    for (int l = 0; l < 2; l++) {
        run_q4gnn(N_ALL, w.adjr, gcn2_w + (long)l * 64 * 256,
                  gcn2_gamma + l * 256, gcn2_beta + l * 256, w.aggA, w, stream);
        run_q4gnn(N_ENTS, w.adj, gcn1_w + (long)l * 64 * 256,
                  gcn1_gamma + l * 256, gcn1_beta + l * 256, w.aggB, w, stream);
        build_ht_kernel<<<(256 * 512) / 256, 256, 0, stream>>>(
            lin_ents + (long)l * 128 * 256, w.ht_hi, w.ht_lo, 128);
        dim3 g(1, (N_ENTS + 127) / 128);
        mfma_lin_kernel<<<g, 256, 0, stream>>>(
            w.aggB, w.aggA, w.ht_hi, w.ht_lo, w.xr_hi, w.xr_lo, N_ENTS);
        // Rels rows: split the q4gnn R-update (aggA tail) into xr directly.
        run_split(w.aggA + (long)N_ENTS * EMB, w.xr_hi + (long)N_ENTS * EMB,
                  w.xr_lo + (long)N_ENTS * EMB, (long)N_RELS * EMB, stream);
        run_score(e1_idx, r_idx, bn_s_gamma + (l + 1) * 256,
                  bn_s_beta + (l + 1) * 256,
                  out + (long)(l + 1) * BATCH * N_ENTS, w, stream);
    }
}